// Round 15
// baseline (111.898 us; speedup 1.0000x reference)
//
#include <hip/hip_runtime.h>
#include <hip/hip_bf16.h>

#define NB 16
#define DMODEL 1024
#define HALFD 512
#define PNUM 4096
#define PLEN 32
#define SEQ 2048
#define SIM 64
#define NPATCH 64
#define NROWS (NB*SEQ)        // 32768 sequence rows
#define MROWS (NB*NPATCH)     // 1024 (b,p) rows
#define KDIM (PLEN*HALFD)     // 16384
#define OUT0 ((size_t)NB*SEQ*DMODEL)

typedef __attribute__((ext_vector_type(8))) short s8v;          // 8 bf16 (4 VGPR)
typedef __attribute__((ext_vector_type(4))) float f32x4;
typedef __attribute__((ext_vector_type(8))) unsigned short ush8;
typedef unsigned long long u64;

__device__ __forceinline__ unsigned short f2bf(float f) {
    __hip_bfloat16 h = __float2bfloat16(f);
    return *reinterpret_cast<unsigned short*>(&h);
}
__device__ __forceinline__ float bf2f(unsigned short u) {
    __hip_bfloat16 h = *reinterpret_cast<__hip_bfloat16*>(&u);
    return __bfloat162float(h);
}
__device__ __forceinline__ u64 umax64(u64 a, u64 b) { return a > b ? a : b; }
__device__ __forceinline__ u64 umin64(u64 a, u64 b) { return a < b ? a : b; }
__device__ __forceinline__ u64 clean6(u64 v, int lane) {
    #pragma unroll
    for (int j = 32; j; j >>= 1) {
        u64 o = __shfl_xor(v, j);
        v = ((lane & j) == 0) ? umax64(v, o) : umin64(v, o);
    }
    return v;
}

// ---- K0: fw pack (0..255) | low (256..767) | rw pack (768..783) ----
union PrepShared {
    float tile[64][68];
    double gpm[513];
};
__global__ __launch_bounds__(256) void k_prep(
        const float* __restrict__ gp_w, const float* __restrict__ gp_b,
        const float* __restrict__ fw, const float* __restrict__ rw,
        const float* __restrict__ src,
        unsigned short* __restrict__ fwT_hi, unsigned short* __restrict__ fwT_lo,
        unsigned short* __restrict__ rwf_hi, unsigned short* __restrict__ rwf_lo,
        double* __restrict__ low) {
    __shared__ PrepShared u;
    int bid = blockIdx.x, t = threadIdx.x;
    if (bid < 256) {
        int k0 = bid * 64;
        int i = t >> 2;
        #pragma unroll
        for (int q = 0; q < 4; ++q) {
            int c = (t & 3) + q*4;
            float4 v = *reinterpret_cast<const float4*>(fw + (size_t)(k0 + i)*SIM + c*4);
            *reinterpret_cast<float4*>(&u.tile[i][c*4]) = v;
        }
        __syncthreads();
        #pragma unroll
        for (int c2 = 0; c2 < 2; ++c2) {
            int e = c2*256 + t;
            int kl = e >> 8, fn = (e >> 6) & 3, l = e & 63;
            int kk0 = kl*32 + ((l >> 4) * 8), n = fn*16 + (l & 15);
            ush8 hv, lv;
            #pragma unroll
            for (int j = 0; j < 8; ++j) {
                float f = u.tile[kk0 + j][n];
                unsigned short hb = f2bf(f);
                hv[j] = hb;
                lv[j] = f2bf(f - bf2f(hb));
            }
            size_t dst = ((size_t)((2*bid + kl)*4 + fn)*64 + l)*8;
            *reinterpret_cast<ush8*>(fwT_hi + dst) = hv;
            *reinterpret_cast<ush8*>(fwT_lo + dst) = lv;
        }
    } else if (bid < 768) {
        for (int h = t; h < HALFD; h += 256) {
            double s = 0.0;
            #pragma unroll
            for (int j = 0; j < 10; ++j) s += (double)gp_w[h*10 + j];
            u.gpm[h] = s / 10.0;
        }
        if (t == 0) {
            double sb = 0.0;
            #pragma unroll
            for (int j = 0; j < 10; ++j) sb += (double)gp_b[j];
            u.gpm[512] = sb / 10.0;
        }
        __syncthreads();
        int r = (bid - 256)*4 + (t >> 6);      // 0..2047
        int lane = t & 63;
        const float4* s4 = reinterpret_cast<const float4*>(src + (size_t)r * DMODEL);
        float4 x0 = s4[128 + lane];
        float4 x1 = s4[192 + lane];
        const double* g0 = u.gpm + lane*4;
        const double* g1 = u.gpm + 256 + lane*4;
        double d = (double)x0.x*g0[0] + (double)x0.y*g0[1] + (double)x0.z*g0[2] + (double)x0.w*g0[3]
                 + (double)x1.x*g1[0] + (double)x1.y*g1[1] + (double)x1.z*g1[2] + (double)x1.w*g1[3];
        #pragma unroll
        for (int o = 32; o; o >>= 1) d += __shfl_xor(d, o);
        if (lane == 0) low[r] = d + u.gpm[512];
    } else {
        int lane = t & 63, q = t >> 6;
        int idx = (bid - 768)*4 + q;           // 0..63 = (ks,fn)
        int ks = idx >> 5, fn = idx & 31;
        int ml = lane & 15, kg = lane >> 4;
        ush8 hv, lv;
        #pragma unroll
        for (int j = 0; j < 8; ++j) {
            float f = rw[(size_t)(ks*32 + kg*8 + j)*HALFD + fn*16 + ml];
            unsigned short hb = f2bf(f);
            hv[j] = hb;
            lv[j] = f2bf(f - bf2f(hb));
        }
        size_t dst = ((size_t)idx*64 + lane)*8;
        *reinterpret_cast<ush8*>(rwf_hi + dst) = hv;
        *reinterpret_cast<ush8*>(rwf_lo + dst) = lv;
    }
}

// ---------------- K2: topk — wave-register bitonic ----------------
__global__ __launch_bounds__(256) void k_topk(
        const double* __restrict__ low, const float* __restrict__ pool,
        u64* __restrict__ cand) {
    __shared__ double lowp[PLEN];
    __shared__ u64 wl[4][64];
    int t = threadIdx.x, lane = t & 63, w = t >> 6;
    int p = blockIdx.x >> 3, q = blockIdx.x & 7;
    if (t < PLEN) lowp[t] = low[p*PLEN + t];
    __syncthreads();
    u64 v[2];
    #pragma unroll
    for (int cc = 0; cc < 2; ++cc) {
        int n = q*512 + (w*2 + cc)*64 + lane;
        const float4* p4 = reinterpret_cast<const float4*>(pool + (size_t)n*PLEN);
        double s = 0.0;
        #pragma unroll
        for (int r2 = 0; r2 < 8; ++r2) {
            float4 vv = p4[r2];
            s += (double)vv.x*lowp[r2*4] + (double)vv.y*lowp[r2*4+1]
               + (double)vv.z*lowp[r2*4+2] + (double)vv.w*lowp[r2*4+3];
        }
        u64 ub = (u64)__double_as_longlong(s);
        u64 okey = ub ^ (((u64)((long long)ub >> 63)) | 0x8000000000000000ULL);
        v[cc] = (okey & ~0xFFFULL) | (u64)(0xFFF - n);
    }
    #pragma unroll
    for (int kk = 2; kk <= 64; kk <<= 1) {
        #pragma unroll
        for (int j = kk >> 1; j; j >>= 1) {
            #pragma unroll
            for (int cc = 0; cc < 2; ++cc) {
                u64 o = __shfl_xor(v[cc], j);
                bool keepMax = ((lane & kk) == 0) == ((lane & j) == 0);
                v[cc] = keepMax ? umax64(v[cc], o) : umin64(v[cc], o);
            }
        }
    }
    u64 rb2 = __shfl(v[1], 63 - lane);
    u64 m = umax64(v[0], rb2);
    m = clean6(m, lane);
    wl[w][lane] = m;
    __syncthreads();
    if (w == 0) {
        u64 a = umax64(wl[0][lane], wl[1][63 - lane]); a = clean6(a, lane);
        u64 b = umax64(wl[2][lane], wl[3][63 - lane]); b = clean6(b, lane);
        u64 r2 = __shfl(b, 63 - lane);
        u64 f = umax64(a, r2); f = clean6(f, lane);
        cand[(size_t)(p*8 + q)*SIM + lane] = f;
    }
}

// ---------------- K3: logits MFMA — direct-global A, packed B, no LDS ----------------
__global__ __launch_bounds__(256) void k_logits(
        const float* __restrict__ src,
        const unsigned short* __restrict__ fwT_hi, const unsigned short* __restrict__ fwT_lo,
        float* __restrict__ part, int nks) {
    int t = threadIdx.x, lane = t & 63, w = t >> 6;
    int mt = blockIdx.x / nks, ks = blockIdx.x - mt*nks;
    int kchunk = KDIM / nks, nstep = kchunk >> 6;
    int r0 = mt*64;
    int ml = lane & 15, kg = lane >> 4;
    int Rrow = r0 + w*16 + ml;
    int bb = Rrow >> 6, prow = Rrow & 63;
    const float* xrow = src + ((size_t)(bb*SEQ + prow*PLEN))*DMODEL + HALFD;
    int kblk_base = (ks*kchunk) >> 5;
    f32x4 acc[4] = {};
    for (int step = 0; step < nstep; ++step) {
        int k0 = ks*kchunk + step*64;
        int l = k0 >> 9, h0 = k0 & 511;
        const float* ap = xrow + (size_t)l*DMODEL + h0 + kg*8;
        float4 va0 = *reinterpret_cast<const float4*>(ap);
        float4 va1 = *reinterpret_cast<const float4*>(ap + 4);
        float4 vb0 = *reinterpret_cast<const float4*>(ap + 32);
        float4 vb1 = *reinterpret_cast<const float4*>(ap + 36);
        s8v ah0, al0, ah1, al1;
        float fa[8] = {va0.x,va0.y,va0.z,va0.w,va1.x,va1.y,va1.z,va1.w};
        float fbv[8] = {vb0.x,vb0.y,vb0.z,vb0.w,vb1.x,vb1.y,vb1.z,vb1.w};
        #pragma unroll
        for (int j = 0; j < 8; ++j) {
            unsigned short hb = f2bf(fa[j]);
            ah0[j] = (short)hb;
            al0[j] = (short)f2bf(fa[j] - bf2f(hb));
            unsigned short hb2 = f2bf(fbv[j]);
            ah1[j] = (short)hb2;
            al1[j] = (short)f2bf(fbv[j] - bf2f(hb2));
        }
        int kblk0 = kblk_base + step*2;
        #pragma unroll
        for (int fn = 0; fn < 4; ++fn) {
            size_t off0 = ((size_t)(kblk0*4 + fn)*64 + lane)*8;
            size_t off1 = ((size_t)((kblk0+1)*4 + fn)*64 + lane)*8;
            s8v bh0 = *reinterpret_cast<const s8v*>(fwT_hi + off0);
            s8v bl0 = *reinterpret_cast<const s8v*>(fwT_lo + off0);
            s8v bh1 = *reinterpret_cast<const s8v*>(fwT_hi + off1);
            s8v bl1 = *reinterpret_cast<const s8v*>(fwT_lo + off1);
            acc[fn] = __builtin_amdgcn_mfma_f32_16x16x32_bf16(ah0, bh0, acc[fn], 0, 0, 0);
            acc[fn] = __builtin_amdgcn_mfma_f32_16x16x32_bf16(ah0, bl0, acc[fn], 0, 0, 0);
            acc[fn] = __builtin_amdgcn_mfma_f32_16x16x32_bf16(al0, bh0, acc[fn], 0, 0, 0);
            acc[fn] = __builtin_amdgcn_mfma_f32_16x16x32_bf16(ah1, bh1, acc[fn], 0, 0, 0);
            acc[fn] = __builtin_amdgcn_mfma_f32_16x16x32_bf16(ah1, bl1, acc[fn], 0, 0, 0);
            acc[fn] = __builtin_amdgcn_mfma_f32_16x16x32_bf16(al1, bh1, acc[fn], 0, 0, 0);
        }
    }
    float* pout = part + (size_t)(mt*nks + ks)*4096;
    #pragma unroll
    for (int fn = 0; fn < 4; ++fn)
        #pragma unroll
        for (int r = 0; r < 4; ++r)
            pout[(w*16 + kg*4 + r)*64 + fn*16 + ml] = acc[fn][r];
}

// ---- K4: out — softmax + merge + A build + MFMA + LDS-transpose float4 stores + copy ----
union OutShared {
    struct { float A_T[SIM][36]; float routeS[64]; int selS[64]; } a;  // 9.7 KB
    float xpose[16][516];                                              // 33 KB
};
__global__ __launch_bounds__(256) void k_out(
        const float* __restrict__ part, const float* __restrict__ fb,
        const u64* __restrict__ cand, const float* __restrict__ pool,
        const unsigned short* __restrict__ rwf_hi, const unsigned short* __restrict__ rwf_lo,
        const float* __restrict__ rb, const float* __restrict__ src,
        float* __restrict__ out, float* __restrict__ pad, int nks) {
    __shared__ OutShared u;
    int row = blockIdx.x;                    // b*64+p
    int b = row >> 6, p = row & 63;
    int t = threadIdx.x, lane = t & 63, w = t >> 6;
    if (w == 0) {
        float v = fb[lane];
        for (int ks = 0; ks < nks; ++ks)
            v += part[(size_t)(b*nks + ks)*4096 + p*64 + lane];
        float m = v;
        #pragma unroll
        for (int o = 32; o; o >>= 1) m = fmaxf(m, __shfl_xor(m, o));
        float e = expf(v - m);
        float sum = e;
        #pragma unroll
        for (int o = 32; o; o >>= 1) sum += __shfl_xor(sum, o);
        u.a.routeS[lane] = e / sum;
    } else if (w == 1) {
        const u64* c = cand + (size_t)p*8*SIM;
        u64 a = umax64(c[lane],         c[1*SIM + 63 - lane]); a = clean6(a, lane);
        u64 bq = umax64(c[2*SIM + lane], c[3*SIM + 63 - lane]); bq = clean6(bq, lane);
        u64 d = umax64(c[4*SIM + lane], c[5*SIM + 63 - lane]); d = clean6(d, lane);
        u64 e = umax64(c[6*SIM + lane], c[7*SIM + 63 - lane]); e = clean6(e, lane);
        u64 ab = umax64(a, __shfl(bq, 63 - lane)); ab = clean6(ab, lane);
        u64 de = umax64(d, __shfl(e, 63 - lane)); de = clean6(de, lane);
        u64 f  = umax64(ab, __shfl(de, 63 - lane)); f = clean6(f, lane);
        u.a.selS[lane] = 0xFFF - (int)(f & 0xFFFULL);
    }
    __syncthreads();
    #pragma unroll
    for (int q = 0; q < 8; ++q) {            // A_T[s][l] = route[s]*pool[sel[s]][l]
        int e = t + q*256;
        int s = e >> 5, l = e & 31;
        u.a.A_T[s][l] = u.a.routeS[s] * pool[(size_t)u.a.selS[s]*PLEN + l];
    }
    __syncthreads();
    if (t < 32) {                            // padding row-sum
        float ps = 0.f;
        #pragma unroll
        for (int s = 0; s < 64; ++s) ps += u.a.A_T[s][t];
        pad[(size_t)b*2*SEQ + SEQ + p*PLEN + t] = ps;
    } else if (t < 64) {
        pad[(size_t)b*2*SEQ + p*PLEN + (t - 32)] = 0.f;
    }
    // A fragments: a[j] = A[m = mt*16+ml][k = ks*32 + kg*8 + j], split bf16
    int ml = lane & 15, kg = lane >> 4;
    s8v ah[2][2], al[2][2];                  // [mt][ks]
    #pragma unroll
    for (int mt = 0; mt < 2; ++mt)
        #pragma unroll
        for (int ks = 0; ks < 2; ++ks) {
            #pragma unroll
            for (int j = 0; j < 8; ++j) {
                float f = u.a.A_T[ks*32 + kg*8 + j][mt*16 + ml];
                unsigned short hb = f2bf(f);
                ah[mt][ks][j] = (short)hb;
                al[mt][ks][j] = (short)f2bf(f - bf2f(hb));
            }
        }
    // MFMA: wave w covers N cols [w*128, w*128+128); bias folded in
    f32x4 accA[8], accB[8];
    #pragma unroll
    for (int nt = 0; nt < 8; ++nt) {
        int fng = w*8 + nt;
        f32x4 acc0 = {}, acc1 = {};
        #pragma unroll
        for (int ks = 0; ks < 2; ++ks) {
            size_t off = ((size_t)(ks*32 + fng)*64 + lane)*8;
            s8v bh = *reinterpret_cast<const s8v*>(rwf_hi + off);
            s8v bl = *reinterpret_cast<const s8v*>(rwf_lo + off);
            acc0 = __builtin_amdgcn_mfma_f32_16x16x32_bf16(ah[0][ks], bh, acc0, 0, 0, 0);
            acc0 = __builtin_amdgcn_mfma_f32_16x16x32_bf16(ah[0][ks], bl, acc0, 0, 0, 0);
            acc0 = __builtin_amdgcn_mfma_f32_16x16x32_bf16(al[0][ks], bh, acc0, 0, 0, 0);
            acc1 = __builtin_amdgcn_mfma_f32_16x16x32_bf16(ah[1][ks], bh, acc1, 0, 0, 0);
            acc1 = __builtin_amdgcn_mfma_f32_16x16x32_bf16(ah[1][ks], bl, acc1, 0, 0, 0);
            acc1 = __builtin_amdgcn_mfma_f32_16x16x32_bf16(al[1][ks], bh, acc1, 0, 0, 0);
        }
        float bias = rb[fng*16 + ml];
        #pragma unroll
        for (int r = 0; r < 4; ++r) { acc0[r] += bias; acc1[r] += bias; }
        accA[nt] = acc0; accB[nt] = acc1;
    }
    // LDS-transpose stores: two phases (m-half 0: rows 0..15, half 1: rows 16..31)
    size_t orow0 = ((size_t)(b*SEQ + p*PLEN))*DMODEL + HALFD;
    #pragma unroll
    for (int mt = 0; mt < 2; ++mt) {
        __syncthreads();                     // A_T dead (mt=0) / prior read done (mt=1)
        #pragma unroll
        for (int nt = 0; nt < 8; ++nt) {
            f32x4 a = (mt == 0) ? accA[nt] : accB[nt];
            #pragma unroll
            for (int r = 0; r < 4; ++r)
                u.xpose[kg*4 + r][w*128 + nt*16 + ml] = a[r];
        }
        __syncthreads();
        #pragma unroll
        for (int q = 0; q < 8; ++q) {
            int e = q*256 + t;               // 16 rows x 128 float4
            int rr = e >> 7, c4 = e & 127;
            float4 v = *reinterpret_cast<float4*>(&u.xpose[rr][c4*4]);
            *reinterpret_cast<float4*>(out + orow0 + (size_t)(mt*16 + rr)*DMODEL + c4*4) = v;
        }
    }
    // copy first halves of this block's 32 rows
    const float4* s4 = reinterpret_cast<const float4*>(src);
    float4* o4 = reinterpret_cast<float4*>(out);
    size_t base = ((size_t)(b*SEQ + p*PLEN))*256;
    #pragma unroll
    for (int e = 0; e < 16; ++e) {
        int idx = e*256 + t;                 // 0..4095
        int rr = idx >> 7, c = idx & 127;
        o4[base + rr*256 + c] = s4[base + rr*256 + c];
    }
}

static const void* by_size(void* const* d_in, const int* in_sizes, int n_in,
                           int want, int fallback) {
    for (int i = 0; i < n_in; ++i) if (in_sizes[i] == want) return d_in[i];
    return d_in[fallback];
}

extern "C" void kernel_launch(void* const* d_in, const int* in_sizes, int n_in,
                              void* d_out, int out_size, void* d_ws, size_t ws_size,
                              hipStream_t stream) {
    const float* src  = (const float*)by_size(d_in, in_sizes, n_in, NB*SEQ*DMODEL, 0);
    const float* pool = (const float*)by_size(d_in, in_sizes, n_in, PNUM*PLEN, 1);
    const float* fw   = (const float*)by_size(d_in, in_sizes, n_in, KDIM*SIM, 2);
    const float* fb   = (const float*)by_size(d_in, in_sizes, n_in, SIM, 3);
    const float* rw   = (const float*)by_size(d_in, in_sizes, n_in, SIM*HALFD, 4);
    const float* rb   = (const float*)by_size(d_in, in_sizes, n_in, HALFD, 5);
    const float* gpw  = (const float*)by_size(d_in, in_sizes, n_in, HALFD*10, 6);
    const float* gpb  = (const float*)by_size(d_in, in_sizes, n_in, 10, 7);
    float* out = (float*)d_out;
    float* pad = out + OUT0;

    int nks = (ws_size >= (size_t)(16u << 20)) ? 32 : 8;

    unsigned short* fwT_hi = (unsigned short*)d_ws;                     // 2 MB
    unsigned short* fwT_lo = fwT_hi + (size_t)SIM*KDIM;                 // 2 MB
    unsigned short* rwf_hi = fwT_lo + (size_t)SIM*KDIM;                 // 64 KB
    unsigned short* rwf_lo = rwf_hi + (size_t)SIM*HALFD;                // 64 KB
    double* low  = (double*)(rwf_lo + (size_t)SIM*HALFD);               // 16 KB
    u64*   cand  = (u64*)(low + 2048);                                  // 256 KB
    float* part  = (float*)(cand + (size_t)NPATCH*8*SIM);               // nks * 256 KB

    hipLaunchKernelGGL(k_prep,   dim3(784),    dim3(256), 0, stream,
                       gpw, gpb, fw, rw, src, fwT_hi, fwT_lo, rwf_hi, rwf_lo, low);
    hipLaunchKernelGGL(k_topk,   dim3(512),    dim3(256), 0, stream, low, pool, cand);
    hipLaunchKernelGGL(k_logits, dim3(16*nks), dim3(256), 0, stream, src, fwT_hi, fwT_lo, part, nks);
    hipLaunchKernelGGL(k_out,    dim3(MROWS),  dim3(256), 0, stream,
                       part, fb, cand, pool, rwf_hi, rwf_lo, rb, src, out, pad, nks);
}

// Round 16
// 101.744 us; speedup vs baseline: 1.0998x; 1.0998x over previous
//
#include <hip/hip_runtime.h>
#include <hip/hip_bf16.h>

#define NB 16
#define DMODEL 1024
#define HALFD 512
#define PNUM 4096
#define PLEN 32
#define SEQ 2048
#define SIM 64
#define NPATCH 64
#define NROWS (NB*SEQ)        // 32768 sequence rows
#define MROWS (NB*NPATCH)     // 1024 (b,p) rows
#define KDIM (PLEN*HALFD)     // 16384
#define NCOPY 512
#define OUT0 ((size_t)NB*SEQ*DMODEL)

typedef __attribute__((ext_vector_type(8))) short s8v;          // 8 bf16 (4 VGPR)
typedef __attribute__((ext_vector_type(4))) float f32x4;
typedef __attribute__((ext_vector_type(8))) unsigned short ush8;
typedef unsigned long long u64;

__device__ __forceinline__ unsigned short f2bf(float f) {
    __hip_bfloat16 h = __float2bfloat16(f);
    return *reinterpret_cast<unsigned short*>(&h);
}
__device__ __forceinline__ float bf2f(unsigned short u) {
    __hip_bfloat16 h = *reinterpret_cast<__hip_bfloat16*>(&u);
    return __bfloat162float(h);
}
__device__ __forceinline__ u64 umax64(u64 a, u64 b) { return a > b ? a : b; }
__device__ __forceinline__ u64 umin64(u64 a, u64 b) { return a < b ? a : b; }
__device__ __forceinline__ u64 clean6(u64 v, int lane) {
    #pragma unroll
    for (int j = 32; j; j >>= 1) {
        u64 o = __shfl_xor(v, j);
        v = ((lane & j) == 0) ? umax64(v, o) : umin64(v, o);
    }
    return v;
}

// ---- K0: fw pack (0..255) | low (256..767) | rw pack (768..783) ----
union PrepShared {
    float tile[64][68];
    double gpm[513];
};
__global__ __launch_bounds__(256) void k_prep(
        const float* __restrict__ gp_w, const float* __restrict__ gp_b,
        const float* __restrict__ fw, const float* __restrict__ rw,
        const float* __restrict__ src,
        unsigned short* __restrict__ fwT_hi, unsigned short* __restrict__ fwT_lo,
        unsigned short* __restrict__ rwf_hi, unsigned short* __restrict__ rwf_lo,
        double* __restrict__ low) {
    __shared__ PrepShared u;
    int bid = blockIdx.x, t = threadIdx.x;
    if (bid < 256) {
        int k0 = bid * 64;
        int i = t >> 2;
        #pragma unroll
        for (int q = 0; q < 4; ++q) {
            int c = (t & 3) + q*4;
            float4 v = *reinterpret_cast<const float4*>(fw + (size_t)(k0 + i)*SIM + c*4);
            *reinterpret_cast<float4*>(&u.tile[i][c*4]) = v;
        }
        __syncthreads();
        #pragma unroll
        for (int c2 = 0; c2 < 2; ++c2) {
            int e = c2*256 + t;
            int kl = e >> 8, fn = (e >> 6) & 3, l = e & 63;
            int kk0 = kl*32 + ((l >> 4) * 8), n = fn*16 + (l & 15);
            ush8 hv, lv;
            #pragma unroll
            for (int j = 0; j < 8; ++j) {
                float f = u.tile[kk0 + j][n];
                unsigned short hb = f2bf(f);
                hv[j] = hb;
                lv[j] = f2bf(f - bf2f(hb));
            }
            size_t dst = ((size_t)((2*bid + kl)*4 + fn)*64 + l)*8;
            *reinterpret_cast<ush8*>(fwT_hi + dst) = hv;
            *reinterpret_cast<ush8*>(fwT_lo + dst) = lv;
        }
    } else if (bid < 768) {
        for (int h = t; h < HALFD; h += 256) {
            double s = 0.0;
            #pragma unroll
            for (int j = 0; j < 10; ++j) s += (double)gp_w[h*10 + j];
            u.gpm[h] = s / 10.0;
        }
        if (t == 0) {
            double sb = 0.0;
            #pragma unroll
            for (int j = 0; j < 10; ++j) sb += (double)gp_b[j];
            u.gpm[512] = sb / 10.0;
        }
        __syncthreads();
        int r = (bid - 256)*4 + (t >> 6);      // 0..2047
        int lane = t & 63;
        const float4* s4 = reinterpret_cast<const float4*>(src + (size_t)r * DMODEL);
        float4 x0 = s4[128 + lane];
        float4 x1 = s4[192 + lane];
        const double* g0 = u.gpm + lane*4;
        const double* g1 = u.gpm + 256 + lane*4;
        double d = (double)x0.x*g0[0] + (double)x0.y*g0[1] + (double)x0.z*g0[2] + (double)x0.w*g0[3]
                 + (double)x1.x*g1[0] + (double)x1.y*g1[1] + (double)x1.z*g1[2] + (double)x1.w*g1[3];
        #pragma unroll
        for (int o = 32; o; o >>= 1) d += __shfl_xor(d, o);
        if (lane == 0) low[r] = d + u.gpm[512];
    } else {
        int lane = t & 63, q = t >> 6;
        int idx = (bid - 768)*4 + q;           // 0..63 = (ks,fn)
        int ks = idx >> 5, fn = idx & 31;
        int ml = lane & 15, kg = lane >> 4;
        ush8 hv, lv;
        #pragma unroll
        for (int j = 0; j < 8; ++j) {
            float f = rw[(size_t)(ks*32 + kg*8 + j)*HALFD + fn*16 + ml];
            unsigned short hb = f2bf(f);
            hv[j] = hb;
            lv[j] = f2bf(f - bf2f(hb));
        }
        size_t dst = ((size_t)idx*64 + lane)*8;
        *reinterpret_cast<ush8*>(rwf_hi + dst) = hv;
        *reinterpret_cast<ush8*>(rwf_lo + dst) = lv;
    }
}

// ---------------- K2: topk — wave-register bitonic ----------------
__global__ __launch_bounds__(256) void k_topk(
        const double* __restrict__ low, const float* __restrict__ pool,
        u64* __restrict__ cand) {
    __shared__ double lowp[PLEN];
    __shared__ u64 wl[4][64];
    int t = threadIdx.x, lane = t & 63, w = t >> 6;
    int p = blockIdx.x >> 3, q = blockIdx.x & 7;
    if (t < PLEN) lowp[t] = low[p*PLEN + t];
    __syncthreads();
    u64 v[2];
    #pragma unroll
    for (int cc = 0; cc < 2; ++cc) {
        int n = q*512 + (w*2 + cc)*64 + lane;
        const float4* p4 = reinterpret_cast<const float4*>(pool + (size_t)n*PLEN);
        double s = 0.0;
        #pragma unroll
        for (int r2 = 0; r2 < 8; ++r2) {
            float4 vv = p4[r2];
            s += (double)vv.x*lowp[r2*4] + (double)vv.y*lowp[r2*4+1]
               + (double)vv.z*lowp[r2*4+2] + (double)vv.w*lowp[r2*4+3];
        }
        u64 ub = (u64)__double_as_longlong(s);
        u64 okey = ub ^ (((u64)((long long)ub >> 63)) | 0x8000000000000000ULL);
        v[cc] = (okey & ~0xFFFULL) | (u64)(0xFFF - n);
    }
    #pragma unroll
    for (int kk = 2; kk <= 64; kk <<= 1) {
        #pragma unroll
        for (int j = kk >> 1; j; j >>= 1) {
            #pragma unroll
            for (int cc = 0; cc < 2; ++cc) {
                u64 o = __shfl_xor(v[cc], j);
                bool keepMax = ((lane & kk) == 0) == ((lane & j) == 0);
                v[cc] = keepMax ? umax64(v[cc], o) : umin64(v[cc], o);
            }
        }
    }
    u64 rb2 = __shfl(v[1], 63 - lane);
    u64 m = umax64(v[0], rb2);
    m = clean6(m, lane);
    wl[w][lane] = m;
    __syncthreads();
    if (w == 0) {
        u64 a = umax64(wl[0][lane], wl[1][63 - lane]); a = clean6(a, lane);
        u64 b = umax64(wl[2][lane], wl[3][63 - lane]); b = clean6(b, lane);
        u64 r2 = __shfl(b, 63 - lane);
        u64 f = umax64(a, r2); f = clean6(f, lane);
        cand[(size_t)(p*8 + q)*SIM + lane] = f;
    }
}

// ---- K3: logits MFMA (blocks 0..16*nks) | first-half copy (next 512) ----
__global__ __launch_bounds__(256) void k_logits(
        const float* __restrict__ src,
        const unsigned short* __restrict__ fwT_hi, const unsigned short* __restrict__ fwT_lo,
        float* __restrict__ part, float* __restrict__ out, int nks) {
    int t = threadIdx.x, lane = t & 63, w = t >> 6;
    if ((int)blockIdx.x >= 16*nks) {
        // ---- copy role: out[:, :512] = src[:, :512], streams on idle BW ----
        int cb = blockIdx.x - 16*nks;
        size_t total = (size_t)NROWS * 128;
        const float4* s4 = reinterpret_cast<const float4*>(src);
        float4* o4 = reinterpret_cast<float4*>(out);
        for (size_t idx = (size_t)cb*256 + t; idx < total; idx += (size_t)NCOPY*256) {
            size_t r = idx >> 7, c = idx & 127;
            o4[r*256 + c] = s4[r*256 + c];
        }
        return;
    }
    int mt = blockIdx.x / nks, ks = blockIdx.x - mt*nks;
    int kchunk = KDIM / nks, nstep = kchunk >> 6;
    int r0 = mt*64;
    int ml = lane & 15, kg = lane >> 4;
    int Rrow = r0 + w*16 + ml;
    int bb = Rrow >> 6, prow = Rrow & 63;
    const float* xrow = src + ((size_t)(bb*SEQ + prow*PLEN))*DMODEL + HALFD;
    int kblk_base = (ks*kchunk) >> 5;
    f32x4 acc[4] = {};
    for (int step = 0; step < nstep; ++step) {
        int k0 = ks*kchunk + step*64;
        int l = k0 >> 9, h0 = k0 & 511;
        const float* ap = xrow + (size_t)l*DMODEL + h0 + kg*8;
        float4 va0 = *reinterpret_cast<const float4*>(ap);
        float4 va1 = *reinterpret_cast<const float4*>(ap + 4);
        float4 vb0 = *reinterpret_cast<const float4*>(ap + 32);
        float4 vb1 = *reinterpret_cast<const float4*>(ap + 36);
        s8v ah0, al0, ah1, al1;
        float fa[8] = {va0.x,va0.y,va0.z,va0.w,va1.x,va1.y,va1.z,va1.w};
        float fbv[8] = {vb0.x,vb0.y,vb0.z,vb0.w,vb1.x,vb1.y,vb1.z,vb1.w};
        #pragma unroll
        for (int j = 0; j < 8; ++j) {
            unsigned short hb = f2bf(fa[j]);
            ah0[j] = (short)hb;
            al0[j] = (short)f2bf(fa[j] - bf2f(hb));
            unsigned short hb2 = f2bf(fbv[j]);
            ah1[j] = (short)hb2;
            al1[j] = (short)f2bf(fbv[j] - bf2f(hb2));
        }
        int kblk0 = kblk_base + step*2;
        #pragma unroll
        for (int fn = 0; fn < 4; ++fn) {
            size_t off0 = ((size_t)(kblk0*4 + fn)*64 + lane)*8;
            size_t off1 = ((size_t)((kblk0+1)*4 + fn)*64 + lane)*8;
            s8v bh0 = *reinterpret_cast<const s8v*>(fwT_hi + off0);
            s8v bl0 = *reinterpret_cast<const s8v*>(fwT_lo + off0);
            s8v bh1 = *reinterpret_cast<const s8v*>(fwT_hi + off1);
            s8v bl1 = *reinterpret_cast<const s8v*>(fwT_lo + off1);
            acc[fn] = __builtin_amdgcn_mfma_f32_16x16x32_bf16(ah0, bh0, acc[fn], 0, 0, 0);
            acc[fn] = __builtin_amdgcn_mfma_f32_16x16x32_bf16(ah0, bl0, acc[fn], 0, 0, 0);
            acc[fn] = __builtin_amdgcn_mfma_f32_16x16x32_bf16(al0, bh0, acc[fn], 0, 0, 0);
            acc[fn] = __builtin_amdgcn_mfma_f32_16x16x32_bf16(ah1, bh1, acc[fn], 0, 0, 0);
            acc[fn] = __builtin_amdgcn_mfma_f32_16x16x32_bf16(ah1, bl1, acc[fn], 0, 0, 0);
            acc[fn] = __builtin_amdgcn_mfma_f32_16x16x32_bf16(al1, bh1, acc[fn], 0, 0, 0);
        }
    }
    float* pout = part + (size_t)(mt*nks + ks)*4096;
    #pragma unroll
    for (int fn = 0; fn < 4; ++fn)
        #pragma unroll
        for (int r = 0; r < 4; ++r)
            pout[(w*16 + kg*4 + r)*64 + fn*16 + ml] = acc[fn][r];
}

// ---- K4: out — all-wave softmax + merge + A build + MFMA + direct stores ----
__global__ __launch_bounds__(256) void k_out(
        const float* __restrict__ part, const float* __restrict__ fb,
        const u64* __restrict__ cand, const float* __restrict__ pool,
        const unsigned short* __restrict__ rwf_hi, const unsigned short* __restrict__ rwf_lo,
        const float* __restrict__ rb, float* __restrict__ out,
        float* __restrict__ pad, int nks) {
    __shared__ float A_T[SIM][36];
    __shared__ float routeS[64];
    __shared__ int   selS[64];
    __shared__ float psum[4][64];
    int row = blockIdx.x;                    // b*64+p
    int b = row >> 6, p = row & 63;
    int t = threadIdx.x, lane = t & 63, w = t >> 6;
    // phase 1a: all waves accumulate partial K-split sums
    int kpw = nks >> 2;
    {
        float v = 0.f;
        for (int kq = 0; kq < kpw; ++kq) {
            int ks = w*kpw + kq;
            v += part[(size_t)(b*nks + ks)*4096 + p*64 + lane];
        }
        psum[w][lane] = v;
    }
    __syncthreads();
    // phase 1b: w0 softmax | w1 merge (concurrent)
    if (w == 0) {
        float v = psum[0][lane] + psum[1][lane] + psum[2][lane] + psum[3][lane] + fb[lane];
        float m = v;
        #pragma unroll
        for (int o = 32; o; o >>= 1) m = fmaxf(m, __shfl_xor(m, o));
        float e = expf(v - m);
        float sum = e;
        #pragma unroll
        for (int o = 32; o; o >>= 1) sum += __shfl_xor(sum, o);
        routeS[lane] = e / sum;
    } else if (w == 1) {
        const u64* c = cand + (size_t)p*8*SIM;
        u64 a = umax64(c[lane],         c[1*SIM + 63 - lane]); a = clean6(a, lane);
        u64 bq = umax64(c[2*SIM + lane], c[3*SIM + 63 - lane]); bq = clean6(bq, lane);
        u64 d = umax64(c[4*SIM + lane], c[5*SIM + 63 - lane]); d = clean6(d, lane);
        u64 e = umax64(c[6*SIM + lane], c[7*SIM + 63 - lane]); e = clean6(e, lane);
        u64 ab = umax64(a, __shfl(bq, 63 - lane)); ab = clean6(ab, lane);
        u64 de = umax64(d, __shfl(e, 63 - lane)); de = clean6(de, lane);
        u64 f  = umax64(ab, __shfl(de, 63 - lane)); f = clean6(f, lane);
        selS[lane] = 0xFFF - (int)(f & 0xFFFULL);
    }
    __syncthreads();
    #pragma unroll
    for (int q = 0; q < 8; ++q) {            // A_T[s][l] = route[s]*pool[sel[s]][l]
        int e = t + q*256;
        int s = e >> 5, l = e & 31;
        A_T[s][l] = routeS[s] * pool[(size_t)selS[s]*PLEN + l];
    }
    __syncthreads();
    if (t < 32) {                            // padding row-sum
        float ps = 0.f;
        #pragma unroll
        for (int s = 0; s < 64; ++s) ps += A_T[s][t];
        pad[(size_t)b*2*SEQ + SEQ + p*PLEN + t] = ps;
    } else if (t < 64) {
        pad[(size_t)b*2*SEQ + p*PLEN + (t - 32)] = 0.f;
    }
    // A fragments: a[j] = A[m = mt*16+ml][k = ks*32 + kg*8 + j], split bf16
    int ml = lane & 15, kg = lane >> 4;
    s8v ah[2][2], al[2][2];                  // [mt][ks]
    #pragma unroll
    for (int mt = 0; mt < 2; ++mt)
        #pragma unroll
        for (int ks = 0; ks < 2; ++ks) {
            #pragma unroll
            for (int j = 0; j < 8; ++j) {
                float f = A_T[ks*32 + kg*8 + j][mt*16 + ml];
                unsigned short hb = f2bf(f);
                ah[mt][ks][j] = (short)hb;
                al[mt][ks][j] = (short)f2bf(f - bf2f(hb));
            }
        }
    // MFMA: wave w covers N cols [w*128, w*128+128)
    size_t orow0 = ((size_t)(b*SEQ + p*PLEN))*DMODEL + HALFD;
    #pragma unroll
    for (int nt = 0; nt < 8; ++nt) {
        int fng = w*8 + nt;
        f32x4 acc0 = {}, acc1 = {};
        #pragma unroll
        for (int ks = 0; ks < 2; ++ks) {
            size_t off = ((size_t)(ks*32 + fng)*64 + lane)*8;
            s8v bh = *reinterpret_cast<const s8v*>(rwf_hi + off);
            s8v bl = *reinterpret_cast<const s8v*>(rwf_lo + off);
            acc0 = __builtin_amdgcn_mfma_f32_16x16x32_bf16(ah[0][ks], bh, acc0, 0, 0, 0);
            acc0 = __builtin_amdgcn_mfma_f32_16x16x32_bf16(ah[0][ks], bl, acc0, 0, 0, 0);
            acc0 = __builtin_amdgcn_mfma_f32_16x16x32_bf16(al[0][ks], bh, acc0, 0, 0, 0);
            acc1 = __builtin_amdgcn_mfma_f32_16x16x32_bf16(ah[1][ks], bh, acc1, 0, 0, 0);
            acc1 = __builtin_amdgcn_mfma_f32_16x16x32_bf16(ah[1][ks], bl, acc1, 0, 0, 0);
            acc1 = __builtin_amdgcn_mfma_f32_16x16x32_bf16(al[1][ks], bh, acc1, 0, 0, 0);
        }
        int n = fng*16 + ml;
        float bias = rb[n];
        #pragma unroll
        for (int r = 0; r < 4; ++r) {
            int m0 = kg*4 + r;
            out[orow0 + (size_t)m0*DMODEL + n]        = acc0[r] + bias;
            out[orow0 + (size_t)(16 + m0)*DMODEL + n] = acc1[r] + bias;
        }
    }
}

static const void* by_size(void* const* d_in, const int* in_sizes, int n_in,
                           int want, int fallback) {
    for (int i = 0; i < n_in; ++i) if (in_sizes[i] == want) return d_in[i];
    return d_in[fallback];
}

extern "C" void kernel_launch(void* const* d_in, const int* in_sizes, int n_in,
                              void* d_out, int out_size, void* d_ws, size_t ws_size,
                              hipStream_t stream) {
    const float* src  = (const float*)by_size(d_in, in_sizes, n_in, NB*SEQ*DMODEL, 0);
    const float* pool = (const float*)by_size(d_in, in_sizes, n_in, PNUM*PLEN, 1);
    const float* fw   = (const float*)by_size(d_in, in_sizes, n_in, KDIM*SIM, 2);
    const float* fb   = (const float*)by_size(d_in, in_sizes, n_in, SIM, 3);
    const float* rw   = (const float*)by_size(d_in, in_sizes, n_in, SIM*HALFD, 4);
    const float* rb   = (const float*)by_size(d_in, in_sizes, n_in, HALFD, 5);
    const float* gpw  = (const float*)by_size(d_in, in_sizes, n_in, HALFD*10, 6);
    const float* gpb  = (const float*)by_size(d_in, in_sizes, n_in, 10, 7);
    float* out = (float*)d_out;
    float* pad = out + OUT0;

    int nks = (ws_size >= (size_t)(16u << 20)) ? 32 : 8;

    unsigned short* fwT_hi = (unsigned short*)d_ws;                     // 2 MB
    unsigned short* fwT_lo = fwT_hi + (size_t)SIM*KDIM;                 // 2 MB
    unsigned short* rwf_hi = fwT_lo + (size_t)SIM*KDIM;                 // 64 KB
    unsigned short* rwf_lo = rwf_hi + (size_t)SIM*HALFD;                // 64 KB
    double* low  = (double*)(rwf_lo + (size_t)SIM*HALFD);               // 16 KB
    u64*   cand  = (u64*)(low + 2048);                                  // 256 KB
    float* part  = (float*)(cand + (size_t)NPATCH*8*SIM);               // nks * 256 KB

    hipLaunchKernelGGL(k_prep,   dim3(784),    dim3(256), 0, stream,
                       gpw, gpb, fw, rw, src, fwT_hi, fwT_lo, rwf_hi, rwf_lo, low);
    hipLaunchKernelGGL(k_topk,   dim3(512),    dim3(256), 0, stream, low, pool, cand);
    hipLaunchKernelGGL(k_logits, dim3(16*nks + NCOPY), dim3(256), 0, stream,
                       src, fwT_hi, fwT_lo, part, out, nks);
    hipLaunchKernelGGL(k_out,    dim3(MROWS),  dim3(256), 0, stream,
                       part, fb, cand, pool, rwf_hi, rwf_lo, rb, out, pad, nks);
}

// Round 17
// 101.473 us; speedup vs baseline: 1.1027x; 1.0027x over previous
//
#include <hip/hip_runtime.h>
#include <hip/hip_bf16.h>

#define NB 16
#define DMODEL 1024
#define HALFD 512
#define PNUM 4096
#define PLEN 32
#define SEQ 2048
#define SIM 64
#define NPATCH 64
#define NROWS (NB*SEQ)        // 32768 sequence rows
#define MROWS (NB*NPATCH)     // 1024 (b,p) rows
#define KDIM (PLEN*HALFD)     // 16384
#define NCOPY 512
#define OUT0 ((size_t)NB*SEQ*DMODEL)

typedef __attribute__((ext_vector_type(8))) short s8v;          // 8 bf16 (4 VGPR)
typedef __attribute__((ext_vector_type(4))) float f32x4;
typedef __attribute__((ext_vector_type(8))) unsigned short ush8;
typedef unsigned long long u64;

__device__ __forceinline__ unsigned short f2bf(float f) {
    __hip_bfloat16 h = __float2bfloat16(f);
    return *reinterpret_cast<unsigned short*>(&h);
}
__device__ __forceinline__ float bf2f(unsigned short u) {
    __hip_bfloat16 h = *reinterpret_cast<__hip_bfloat16*>(&u);
    return __bfloat162float(h);
}
__device__ __forceinline__ u64 umax64(u64 a, u64 b) { return a > b ? a : b; }
__device__ __forceinline__ u64 umin64(u64 a, u64 b) { return a < b ? a : b; }
__device__ __forceinline__ u64 clean6(u64 v, int lane) {
    #pragma unroll
    for (int j = 32; j; j >>= 1) {
        u64 o = __shfl_xor(v, j);
        v = ((lane & j) == 0) ? umax64(v, o) : umin64(v, o);
    }
    return v;
}

// ---- D1: topk self-contained (0..511) | fw pack (512..767) | rw pack (768..783) ----
union PrepShared {
    struct { double gpm[513]; double lowp[PLEN]; u64 wl[4][64]; } tk;  // 6.4 KB
    float tile[64][68];                                                // 17.4 KB
};
__global__ __launch_bounds__(256) void k_prep(
        const float* __restrict__ gp_w, const float* __restrict__ gp_b,
        const float* __restrict__ fw, const float* __restrict__ rw,
        const float* __restrict__ src, const float* __restrict__ pool,
        unsigned short* __restrict__ fwT_hi, unsigned short* __restrict__ fwT_lo,
        unsigned short* __restrict__ rwf_hi, unsigned short* __restrict__ rwf_lo,
        u64* __restrict__ cand) {
    __shared__ PrepShared u;
    int bid = blockIdx.x, t = threadIdx.x;
    int lane = t & 63, w = t >> 6;
    if (bid < 512) {
        // ---- topk role: own gp means + own lowp + scores + wave-reg bitonic ----
        int p = bid >> 3, q = bid & 7;
        for (int h = t; h < HALFD; h += 256) {
            double s = 0.0;
            #pragma unroll
            for (int j = 0; j < 10; ++j) s += (double)gp_w[h*10 + j];
            u.tk.gpm[h] = s / 10.0;
        }
        if (t == 0) {
            double sb = 0.0;
            #pragma unroll
            for (int j = 0; j < 10; ++j) sb += (double)gp_b[j];
            u.tk.gpm[512] = sb / 10.0;
        }
        __syncthreads();
        {   // lowp: wave w computes rows w*8..w*8+7 (batch-0 rows of patch p)
            const double* g0 = u.tk.gpm + lane*4;
            const double* g1 = u.tk.gpm + 256 + lane*4;
            #pragma unroll
            for (int rr = 0; rr < 8; ++rr) {
                int r = w*8 + rr;
                const float4* s4 = reinterpret_cast<const float4*>(src + (size_t)(p*PLEN + r)*DMODEL);
                float4 x0 = s4[128 + lane], x1 = s4[192 + lane];
                double d = (double)x0.x*g0[0] + (double)x0.y*g0[1] + (double)x0.z*g0[2] + (double)x0.w*g0[3]
                         + (double)x1.x*g1[0] + (double)x1.y*g1[1] + (double)x1.z*g1[2] + (double)x1.w*g1[3];
                #pragma unroll
                for (int o = 32; o; o >>= 1) d += __shfl_xor(d, o);
                if (lane == 0) u.tk.lowp[r] = d + u.tk.gpm[512];
            }
        }
        __syncthreads();
        u64 v[2];
        #pragma unroll
        for (int cc = 0; cc < 2; ++cc) {
            int n = q*512 + (w*2 + cc)*64 + lane;
            const float4* p4 = reinterpret_cast<const float4*>(pool + (size_t)n*PLEN);
            double s = 0.0;
            #pragma unroll
            for (int r2 = 0; r2 < 8; ++r2) {
                float4 vv = p4[r2];
                s += (double)vv.x*u.tk.lowp[r2*4] + (double)vv.y*u.tk.lowp[r2*4+1]
                   + (double)vv.z*u.tk.lowp[r2*4+2] + (double)vv.w*u.tk.lowp[r2*4+3];
            }
            u64 ub = (u64)__double_as_longlong(s);
            u64 okey = ub ^ (((u64)((long long)ub >> 63)) | 0x8000000000000000ULL);
            v[cc] = (okey & ~0xFFFULL) | (u64)(0xFFF - n);
        }
        #pragma unroll
        for (int kk = 2; kk <= 64; kk <<= 1) {
            #pragma unroll
            for (int j = kk >> 1; j; j >>= 1) {
                #pragma unroll
                for (int cc = 0; cc < 2; ++cc) {
                    u64 o = __shfl_xor(v[cc], j);
                    bool keepMax = ((lane & kk) == 0) == ((lane & j) == 0);
                    v[cc] = keepMax ? umax64(v[cc], o) : umin64(v[cc], o);
                }
            }
        }
        u64 rb2 = __shfl(v[1], 63 - lane);
        u64 m = umax64(v[0], rb2);
        m = clean6(m, lane);
        u.tk.wl[w][lane] = m;
        __syncthreads();
        if (w == 0) {
            u64 a = umax64(u.tk.wl[0][lane], u.tk.wl[1][63 - lane]); a = clean6(a, lane);
            u64 b = umax64(u.tk.wl[2][lane], u.tk.wl[3][63 - lane]); b = clean6(b, lane);
            u64 r2 = __shfl(b, 63 - lane);
            u64 f = umax64(a, r2); f = clean6(f, lane);
            cand[(size_t)(p*8 + q)*SIM + lane] = f;
        }
    } else if (bid < 768) {
        // ---- pack fw -> MFMA B-fragment order, bf16 hi/lo ----
        int k0 = (bid - 512) * 64;
        int i = t >> 2;
        #pragma unroll
        for (int q = 0; q < 4; ++q) {
            int c = (t & 3) + q*4;
            float4 v = *reinterpret_cast<const float4*>(fw + (size_t)(k0 + i)*SIM + c*4);
            *reinterpret_cast<float4*>(&u.tile[i][c*4]) = v;
        }
        __syncthreads();
        #pragma unroll
        for (int c2 = 0; c2 < 2; ++c2) {
            int e = c2*256 + t;
            int kl = e >> 8, fn = (e >> 6) & 3, l = e & 63;
            int kk0 = kl*32 + ((l >> 4) * 8), n = fn*16 + (l & 15);
            ush8 hv, lv;
            #pragma unroll
            for (int j = 0; j < 8; ++j) {
                float f = u.tile[kk0 + j][n];
                unsigned short hb = f2bf(f);
                hv[j] = hb;
                lv[j] = f2bf(f - bf2f(hb));
            }
            size_t dst = ((size_t)((2*(bid - 512) + kl)*4 + fn)*64 + l)*8;
            *reinterpret_cast<ush8*>(fwT_hi + dst) = hv;
            *reinterpret_cast<ush8*>(fwT_lo + dst) = lv;
        }
    } else {
        // ---- pack rw (64x512) -> MFMA B-fragment order, bf16 hi/lo ----
        int q = t >> 6;
        int idx = (bid - 768)*4 + q;           // 0..63 = (ks,fn)
        int ks = idx >> 5, fn = idx & 31;
        int ml = lane & 15, kg = lane >> 4;
        ush8 hv, lv;
        #pragma unroll
        for (int j = 0; j < 8; ++j) {
            float f = rw[(size_t)(ks*32 + kg*8 + j)*HALFD + fn*16 + ml];
            unsigned short hb = f2bf(f);
            hv[j] = hb;
            lv[j] = f2bf(f - bf2f(hb));
        }
        size_t dst = ((size_t)idx*64 + lane)*8;
        *reinterpret_cast<ush8*>(rwf_hi + dst) = hv;
        *reinterpret_cast<ush8*>(rwf_lo + dst) = lv;
    }
}

// ---- D2: logits MFMA (0..16*nks-1, XCD-swizzled) | first-half copy (next 512) ----
__global__ __launch_bounds__(256) void k_logits(
        const float* __restrict__ src,
        const unsigned short* __restrict__ fwT_hi, const unsigned short* __restrict__ fwT_lo,
        float* __restrict__ part, float* __restrict__ out, int nks) {
    int t = threadIdx.x, lane = t & 63, w = t >> 6;
    int bid = blockIdx.x;
    if (bid >= 16*nks) {
        // ---- copy role: out[:, :512] = src[:, :512] ----
        int cb = bid - 16*nks;
        size_t total = (size_t)NROWS * 128;
        const float4* s4 = reinterpret_cast<const float4*>(src);
        float4* o4 = reinterpret_cast<float4*>(out);
        for (size_t idx = (size_t)cb*256 + t; idx < total; idx += (size_t)NCOPY*256) {
            size_t r = idx >> 7, c = idx & 127;
            o4[r*256 + c] = s4[r*256 + c];
        }
        return;
    }
    int g = (bid & 7)*(2*nks) + (bid >> 3);    // XCD swizzle: same-mt blocks colocate
    int mt = g / nks, ks = g - mt*nks;
    int kchunk = KDIM / nks, nstep = kchunk >> 6;
    int r0 = mt*64;
    int ml = lane & 15, kg = lane >> 4;
    int Rrow = r0 + w*16 + ml;
    int bb = Rrow >> 6, prow = Rrow & 63;
    const float* xrow = src + ((size_t)(bb*SEQ + prow*PLEN))*DMODEL + HALFD;
    int kblk_base = (ks*kchunk) >> 5;
    f32x4 acc[4] = {};
    for (int step = 0; step < nstep; ++step) {
        int k0 = ks*kchunk + step*64;
        int l = k0 >> 9, h0 = k0 & 511;
        const float* ap = xrow + (size_t)l*DMODEL + h0 + kg*8;
        float4 va0 = *reinterpret_cast<const float4*>(ap);
        float4 va1 = *reinterpret_cast<const float4*>(ap + 4);
        float4 vb0 = *reinterpret_cast<const float4*>(ap + 32);
        float4 vb1 = *reinterpret_cast<const float4*>(ap + 36);
        s8v ah0, al0, ah1, al1;
        float fa[8] = {va0.x,va0.y,va0.z,va0.w,va1.x,va1.y,va1.z,va1.w};
        float fbv[8] = {vb0.x,vb0.y,vb0.z,vb0.w,vb1.x,vb1.y,vb1.z,vb1.w};
        #pragma unroll
        for (int j = 0; j < 8; ++j) {
            unsigned short hb = f2bf(fa[j]);
            ah0[j] = (short)hb;
            al0[j] = (short)f2bf(fa[j] - bf2f(hb));
            unsigned short hb2 = f2bf(fbv[j]);
            ah1[j] = (short)hb2;
            al1[j] = (short)f2bf(fbv[j] - bf2f(hb2));
        }
        int kblk0 = kblk_base + step*2;
        #pragma unroll
        for (int fn = 0; fn < 4; ++fn) {
            size_t off0 = ((size_t)(kblk0*4 + fn)*64 + lane)*8;
            size_t off1 = ((size_t)((kblk0+1)*4 + fn)*64 + lane)*8;
            s8v bh0 = *reinterpret_cast<const s8v*>(fwT_hi + off0);
            s8v bl0 = *reinterpret_cast<const s8v*>(fwT_lo + off0);
            s8v bh1 = *reinterpret_cast<const s8v*>(fwT_hi + off1);
            s8v bl1 = *reinterpret_cast<const s8v*>(fwT_lo + off1);
            acc[fn] = __builtin_amdgcn_mfma_f32_16x16x32_bf16(ah0, bh0, acc[fn], 0, 0, 0);
            acc[fn] = __builtin_amdgcn_mfma_f32_16x16x32_bf16(ah0, bl0, acc[fn], 0, 0, 0);
            acc[fn] = __builtin_amdgcn_mfma_f32_16x16x32_bf16(al0, bh0, acc[fn], 0, 0, 0);
            acc[fn] = __builtin_amdgcn_mfma_f32_16x16x32_bf16(ah1, bh1, acc[fn], 0, 0, 0);
            acc[fn] = __builtin_amdgcn_mfma_f32_16x16x32_bf16(ah1, bl1, acc[fn], 0, 0, 0);
            acc[fn] = __builtin_amdgcn_mfma_f32_16x16x32_bf16(al1, bh1, acc[fn], 0, 0, 0);
        }
    }
    float* pout = part + (size_t)(mt*nks + ks)*4096;
    #pragma unroll
    for (int fn = 0; fn < 4; ++fn)
        #pragma unroll
        for (int r = 0; r < 4; ++r)
            pout[(w*16 + kg*4 + r)*64 + fn*16 + ml] = acc[fn][r];
}

// ---- D3: out — all-wave psum + softmax|merge + A build + MFMA + stores (XCD-swizzled) ----
__global__ __launch_bounds__(256) void k_out(
        const float* __restrict__ part, const float* __restrict__ fb,
        const u64* __restrict__ cand, const float* __restrict__ pool,
        const unsigned short* __restrict__ rwf_hi, const unsigned short* __restrict__ rwf_lo,
        const float* __restrict__ rb, float* __restrict__ out,
        float* __restrict__ pad, int nks) {
    __shared__ float A_T[SIM][36];
    __shared__ float routeS[64];
    __shared__ int   selS[64];
    __shared__ float psum[4][64];
    int row = (blockIdx.x & 7)*(MROWS/8) + (blockIdx.x >> 3);  // XCD swizzle
    int b = row >> 6, p = row & 63;
    int t = threadIdx.x, lane = t & 63, w = t >> 6;
    int kpw = nks >> 2;
    {
        float v = 0.f;
        for (int kq = 0; kq < kpw; ++kq) {
            int ks = w*kpw + kq;
            v += part[(size_t)(b*nks + ks)*4096 + p*64 + lane];
        }
        psum[w][lane] = v;
    }
    __syncthreads();
    if (w == 0) {
        float v = psum[0][lane] + psum[1][lane] + psum[2][lane] + psum[3][lane] + fb[lane];
        float m = v;
        #pragma unroll
        for (int o = 32; o; o >>= 1) m = fmaxf(m, __shfl_xor(m, o));
        float e = expf(v - m);
        float sum = e;
        #pragma unroll
        for (int o = 32; o; o >>= 1) sum += __shfl_xor(sum, o);
        routeS[lane] = e / sum;
    } else if (w == 1) {
        const u64* c = cand + (size_t)p*8*SIM;
        u64 a = umax64(c[lane],         c[1*SIM + 63 - lane]); a = clean6(a, lane);
        u64 bq = umax64(c[2*SIM + lane], c[3*SIM + 63 - lane]); bq = clean6(bq, lane);
        u64 d = umax64(c[4*SIM + lane], c[5*SIM + 63 - lane]); d = clean6(d, lane);
        u64 e = umax64(c[6*SIM + lane], c[7*SIM + 63 - lane]); e = clean6(e, lane);
        u64 ab = umax64(a, __shfl(bq, 63 - lane)); ab = clean6(ab, lane);
        u64 de = umax64(d, __shfl(e, 63 - lane)); de = clean6(de, lane);
        u64 f  = umax64(ab, __shfl(de, 63 - lane)); f = clean6(f, lane);
        selS[lane] = 0xFFF - (int)(f & 0xFFFULL);
    }
    __syncthreads();
    #pragma unroll
    for (int q = 0; q < 8; ++q) {            // A_T[s][l] = route[s]*pool[sel[s]][l]
        int e = t + q*256;
        int s = e >> 5, l = e & 31;
        A_T[s][l] = routeS[s] * pool[(size_t)selS[s]*PLEN + l];
    }
    __syncthreads();
    if (t < 32) {                            // padding row-sum
        float ps = 0.f;
        #pragma unroll
        for (int s = 0; s < 64; ++s) ps += A_T[s][t];
        pad[(size_t)b*2*SEQ + SEQ + p*PLEN + t] = ps;
    } else if (t < 64) {
        pad[(size_t)b*2*SEQ + p*PLEN + (t - 32)] = 0.f;
    }
    int ml = lane & 15, kg = lane >> 4;
    s8v ah[2][2], al[2][2];                  // [mt][ks]
    #pragma unroll
    for (int mt = 0; mt < 2; ++mt)
        #pragma unroll
        for (int ks = 0; ks < 2; ++ks) {
            #pragma unroll
            for (int j = 0; j < 8; ++j) {
                float f = A_T[ks*32 + kg*8 + j][mt*16 + ml];
                unsigned short hb = f2bf(f);
                ah[mt][ks][j] = (short)hb;
                al[mt][ks][j] = (short)f2bf(f - bf2f(hb));
            }
        }
    size_t orow0 = ((size_t)(b*SEQ + p*PLEN))*DMODEL + HALFD;
    #pragma unroll
    for (int nt = 0; nt < 8; ++nt) {
        int fng = w*8 + nt;
        f32x4 acc0 = {}, acc1 = {};
        #pragma unroll
        for (int ks = 0; ks < 2; ++ks) {
            size_t off = ((size_t)(ks*32 + fng)*64 + lane)*8;
            s8v bh = *reinterpret_cast<const s8v*>(rwf_hi + off);
            s8v bl = *reinterpret_cast<const s8v*>(rwf_lo + off);
            acc0 = __builtin_amdgcn_mfma_f32_16x16x32_bf16(ah[0][ks], bh, acc0, 0, 0, 0);
            acc0 = __builtin_amdgcn_mfma_f32_16x16x32_bf16(ah[0][ks], bl, acc0, 0, 0, 0);
            acc0 = __builtin_amdgcn_mfma_f32_16x16x32_bf16(al[0][ks], bh, acc0, 0, 0, 0);
            acc1 = __builtin_amdgcn_mfma_f32_16x16x32_bf16(ah[1][ks], bh, acc1, 0, 0, 0);
            acc1 = __builtin_amdgcn_mfma_f32_16x16x32_bf16(ah[1][ks], bl, acc1, 0, 0, 0);
            acc1 = __builtin_amdgcn_mfma_f32_16x16x32_bf16(al[1][ks], bh, acc1, 0, 0, 0);
        }
        int n = fng*16 + ml;
        float bias = rb[n];
        #pragma unroll
        for (int r = 0; r < 4; ++r) {
            int m0 = kg*4 + r;
            out[orow0 + (size_t)m0*DMODEL + n]        = acc0[r] + bias;
            out[orow0 + (size_t)(16 + m0)*DMODEL + n] = acc1[r] + bias;
        }
    }
}

static const void* by_size(void* const* d_in, const int* in_sizes, int n_in,
                           int want, int fallback) {
    for (int i = 0; i < n_in; ++i) if (in_sizes[i] == want) return d_in[i];
    return d_in[fallback];
}

extern "C" void kernel_launch(void* const* d_in, const int* in_sizes, int n_in,
                              void* d_out, int out_size, void* d_ws, size_t ws_size,
                              hipStream_t stream) {
    const float* src  = (const float*)by_size(d_in, in_sizes, n_in, NB*SEQ*DMODEL, 0);
    const float* pool = (const float*)by_size(d_in, in_sizes, n_in, PNUM*PLEN, 1);
    const float* fw   = (const float*)by_size(d_in, in_sizes, n_in, KDIM*SIM, 2);
    const float* fb   = (const float*)by_size(d_in, in_sizes, n_in, SIM, 3);
    const float* rw   = (const float*)by_size(d_in, in_sizes, n_in, SIM*HALFD, 4);
    const float* rb   = (const float*)by_size(d_in, in_sizes, n_in, HALFD, 5);
    const float* gpw  = (const float*)by_size(d_in, in_sizes, n_in, HALFD*10, 6);
    const float* gpb  = (const float*)by_size(d_in, in_sizes, n_in, 10, 7);
    float* out = (float*)d_out;
    float* pad = out + OUT0;

    int nks = (ws_size >= (size_t)(16u << 20)) ? 32 : 8;

    unsigned short* fwT_hi = (unsigned short*)d_ws;                     // 2 MB
    unsigned short* fwT_lo = fwT_hi + (size_t)SIM*KDIM;                 // 2 MB
    unsigned short* rwf_hi = fwT_lo + (size_t)SIM*KDIM;                 // 64 KB
    unsigned short* rwf_lo = rwf_hi + (size_t)SIM*HALFD;                // 64 KB
    u64*   cand  = (u64*)(rwf_lo + (size_t)SIM*HALFD);                  // 256 KB
    float* part  = (float*)(cand + (size_t)NPATCH*8*SIM);               // nks * 256 KB

    hipLaunchKernelGGL(k_prep,   dim3(784),    dim3(256), 0, stream,
                       gpw, gpb, fw, rw, src, pool, fwT_hi, fwT_lo, rwf_hi, rwf_lo, cand);
    hipLaunchKernelGGL(k_logits, dim3(16*nks + NCOPY), dim3(256), 0, stream,
                       src, fwT_hi, fwT_lo, part, out, nks);
    hipLaunchKernelGGL(k_out,    dim3(MROWS),  dim3(256), 0, stream,
                       part, fb, cand, pool, rwf_hi, rwf_lo, rb, out, pad, nks);
}

// Round 18
// 90.637 us; speedup vs baseline: 1.2346x; 1.1195x over previous
//
#include <hip/hip_runtime.h>
#include <hip/hip_bf16.h>

#define NB 16
#define DMODEL 1024
#define HALFD 512
#define PNUM 4096
#define PLEN 32
#define SEQ 2048
#define SIM 64
#define NPATCH 64
#define NROWS (NB*SEQ)        // 32768 sequence rows
#define MROWS (NB*NPATCH)     // 1024 (b,p) rows
#define KDIM (PLEN*HALFD)     // 16384
#define NCOPY 512
#define OUT0 ((size_t)NB*SEQ*DMODEL)

typedef __attribute__((ext_vector_type(8))) short s8v;          // 8 bf16 (4 VGPR)
typedef __attribute__((ext_vector_type(4))) float f32x4;
typedef __attribute__((ext_vector_type(8))) unsigned short ush8;
typedef unsigned long long u64;

__device__ __forceinline__ unsigned short f2bf(float f) {
    __hip_bfloat16 h = __float2bfloat16(f);
    return *reinterpret_cast<unsigned short*>(&h);
}
__device__ __forceinline__ u64 umax64(u64 a, u64 b) { return a > b ? a : b; }
__device__ __forceinline__ u64 umin64(u64 a, u64 b) { return a < b ? a : b; }
__device__ __forceinline__ u64 clean6(u64 v, int lane) {
    #pragma unroll
    for (int j = 32; j; j >>= 1) {
        u64 o = __shfl_xor(v, j);
        v = ((lane & j) == 0) ? umax64(v, o) : umin64(v, o);
    }
    return v;
}

// ---- D1: topk self-contained (0..511) | fw pack (512..767) | rw pack (768..783) ----
union PrepShared {
    struct { double gpm[513]; double lowp[PLEN]; u64 wl[4][64]; } tk;  // 6.4 KB
    float tile[64][68];                                                // 17.4 KB
};
__global__ __launch_bounds__(256) void k_prep(
        const float* __restrict__ gp_w, const float* __restrict__ gp_b,
        const float* __restrict__ fw, const float* __restrict__ rw,
        const float* __restrict__ src, const float* __restrict__ pool,
        unsigned short* __restrict__ fwT, unsigned short* __restrict__ rwf,
        u64* __restrict__ cand) {
    __shared__ PrepShared u;
    int bid = blockIdx.x, t = threadIdx.x;
    int lane = t & 63, w = t >> 6;
    if (bid < 512) {
        // ---- topk role: own gp means + own lowp + scores + wave-reg bitonic ----
        int p = bid >> 3, q = bid & 7;
        for (int h = t; h < HALFD; h += 256) {
            double s = 0.0;
            #pragma unroll
            for (int j = 0; j < 10; ++j) s += (double)gp_w[h*10 + j];
            u.tk.gpm[h] = s / 10.0;
        }
        if (t == 0) {
            double sb = 0.0;
            #pragma unroll
            for (int j = 0; j < 10; ++j) sb += (double)gp_b[j];
            u.tk.gpm[512] = sb / 10.0;
        }
        __syncthreads();
        {   // lowp: wave w computes rows w*8..w*8+7 (batch-0 rows of patch p)
            const double* g0 = u.tk.gpm + lane*4;
            const double* g1 = u.tk.gpm + 256 + lane*4;
            #pragma unroll
            for (int rr = 0; rr < 8; ++rr) {
                int r = w*8 + rr;
                const float4* s4 = reinterpret_cast<const float4*>(src + (size_t)(p*PLEN + r)*DMODEL);
                float4 x0 = s4[128 + lane], x1 = s4[192 + lane];
                double d = (double)x0.x*g0[0] + (double)x0.y*g0[1] + (double)x0.z*g0[2] + (double)x0.w*g0[3]
                         + (double)x1.x*g1[0] + (double)x1.y*g1[1] + (double)x1.z*g1[2] + (double)x1.w*g1[3];
                #pragma unroll
                for (int o = 32; o; o >>= 1) d += __shfl_xor(d, o);
                if (lane == 0) u.tk.lowp[r] = d + u.tk.gpm[512];
            }
        }
        __syncthreads();
        u64 v[2];
        #pragma unroll
        for (int cc = 0; cc < 2; ++cc) {
            int n = q*512 + (w*2 + cc)*64 + lane;
            const float4* p4 = reinterpret_cast<const float4*>(pool + (size_t)n*PLEN);
            double s = 0.0;
            #pragma unroll
            for (int r2 = 0; r2 < 8; ++r2) {
                float4 vv = p4[r2];
                s += (double)vv.x*u.tk.lowp[r2*4] + (double)vv.y*u.tk.lowp[r2*4+1]
                   + (double)vv.z*u.tk.lowp[r2*4+2] + (double)vv.w*u.tk.lowp[r2*4+3];
            }
            u64 ub = (u64)__double_as_longlong(s);
            u64 okey = ub ^ (((u64)((long long)ub >> 63)) | 0x8000000000000000ULL);
            v[cc] = (okey & ~0xFFFULL) | (u64)(0xFFF - n);
        }
        #pragma unroll
        for (int kk = 2; kk <= 64; kk <<= 1) {
            #pragma unroll
            for (int j = kk >> 1; j; j >>= 1) {
                #pragma unroll
                for (int cc = 0; cc < 2; ++cc) {
                    u64 o = __shfl_xor(v[cc], j);
                    bool keepMax = ((lane & kk) == 0) == ((lane & j) == 0);
                    v[cc] = keepMax ? umax64(v[cc], o) : umin64(v[cc], o);
                }
            }
        }
        u64 rb2 = __shfl(v[1], 63 - lane);
        u64 m = umax64(v[0], rb2);
        m = clean6(m, lane);
        u.tk.wl[w][lane] = m;
        __syncthreads();
        if (w == 0) {
            u64 a = umax64(u.tk.wl[0][lane], u.tk.wl[1][63 - lane]); a = clean6(a, lane);
            u64 b = umax64(u.tk.wl[2][lane], u.tk.wl[3][63 - lane]); b = clean6(b, lane);
            u64 r2 = __shfl(b, 63 - lane);
            u64 f = umax64(a, r2); f = clean6(f, lane);
            cand[(size_t)(p*8 + q)*SIM + lane] = f;
        }
    } else if (bid < 768) {
        // ---- pack fw -> MFMA B-fragment order, plain bf16 ----
        int k0 = (bid - 512) * 64;
        int i = t >> 2;
        #pragma unroll
        for (int q = 0; q < 4; ++q) {
            int c = (t & 3) + q*4;
            float4 v = *reinterpret_cast<const float4*>(fw + (size_t)(k0 + i)*SIM + c*4);
            *reinterpret_cast<float4*>(&u.tile[i][c*4]) = v;
        }
        __syncthreads();
        #pragma unroll
        for (int c2 = 0; c2 < 2; ++c2) {
            int e = c2*256 + t;
            int kl = e >> 8, fn = (e >> 6) & 3, l = e & 63;
            int kk0 = kl*32 + ((l >> 4) * 8), n = fn*16 + (l & 15);
            ush8 hv;
            #pragma unroll
            for (int j = 0; j < 8; ++j) hv[j] = f2bf(u.tile[kk0 + j][n]);
            size_t dst = ((size_t)((2*(bid - 512) + kl)*4 + fn)*64 + l)*8;
            *reinterpret_cast<ush8*>(fwT + dst) = hv;
        }
    } else {
        // ---- pack rw (64x512) -> MFMA B-fragment order, plain bf16 ----
        int q = t >> 6;
        int idx = (bid - 768)*4 + q;           // 0..63 = (ks,fn)
        int ks = idx >> 5, fn = idx & 31;
        int ml = lane & 15, kg = lane >> 4;
        ush8 hv;
        #pragma unroll
        for (int j = 0; j < 8; ++j)
            hv[j] = f2bf(rw[(size_t)(ks*32 + kg*8 + j)*HALFD + fn*16 + ml]);
        size_t dst = ((size_t)idx*64 + lane)*8;
        *reinterpret_cast<ush8*>(rwf + dst) = hv;
    }
}

// ---- D2: logits MFMA (0..16*nks-1) | copy (next 512) | sel merge (next 64) ----
__global__ __launch_bounds__(256) void k_logits(
        const float* __restrict__ src, const unsigned short* __restrict__ fwT,
        const u64* __restrict__ cand, float* __restrict__ part,
        float* __restrict__ out, int* __restrict__ sel, int nks) {
    int t = threadIdx.x, lane = t & 63, w = t >> 6;
    int bid = blockIdx.x;
    int NL = 16*nks;
    if (bid >= NL + NCOPY) {
        // ---- sel merge role: one block per patch ----
        if (w != 0) return;
        int p = bid - (NL + NCOPY);
        const u64* c = cand + (size_t)p*8*SIM;
        u64 a = umax64(c[lane],         c[1*SIM + 63 - lane]); a = clean6(a, lane);
        u64 bq = umax64(c[2*SIM + lane], c[3*SIM + 63 - lane]); bq = clean6(bq, lane);
        u64 d = umax64(c[4*SIM + lane], c[5*SIM + 63 - lane]); d = clean6(d, lane);
        u64 e = umax64(c[6*SIM + lane], c[7*SIM + 63 - lane]); e = clean6(e, lane);
        u64 ab = umax64(a, __shfl(bq, 63 - lane)); ab = clean6(ab, lane);
        u64 de = umax64(d, __shfl(e, 63 - lane)); de = clean6(de, lane);
        u64 f  = umax64(ab, __shfl(de, 63 - lane)); f = clean6(f, lane);
        sel[p*SIM + lane] = 0xFFF - (int)(f & 0xFFFULL);
        return;
    }
    if (bid >= NL) {
        // ---- copy role: out[:, :512] = src[:, :512] ----
        int cb = bid - NL;
        size_t total = (size_t)NROWS * 128;
        const float4* s4 = reinterpret_cast<const float4*>(src);
        float4* o4 = reinterpret_cast<float4*>(out);
        for (size_t idx = (size_t)cb*256 + t; idx < total; idx += (size_t)NCOPY*256) {
            size_t r = idx >> 7, c = idx & 127;
            o4[r*256 + c] = s4[r*256 + c];
        }
        return;
    }
    int mt = bid / nks, ks = bid - mt*nks;
    int kchunk = KDIM / nks, nstep = kchunk >> 6;
    int r0 = mt*64;
    int ml = lane & 15, kg = lane >> 4;
    int Rrow = r0 + w*16 + ml;
    int bb = Rrow >> 6, prow = Rrow & 63;
    const float* xrow = src + ((size_t)(bb*SEQ + prow*PLEN))*DMODEL + HALFD;
    int kblk_base = (ks*kchunk) >> 5;
    f32x4 acc[4] = {};
    for (int step = 0; step < nstep; ++step) {
        int k0 = ks*kchunk + step*64;
        int l = k0 >> 9, h0 = k0 & 511;          // 64-chunk never crosses l
        const float* ap = xrow + (size_t)l*DMODEL + h0 + kg*8;
        float4 va0 = *reinterpret_cast<const float4*>(ap);
        float4 va1 = *reinterpret_cast<const float4*>(ap + 4);
        float4 vb0 = *reinterpret_cast<const float4*>(ap + 32);
        float4 vb1 = *reinterpret_cast<const float4*>(ap + 36);
        s8v ah0, ah1;
        float fa[8] = {va0.x,va0.y,va0.z,va0.w,va1.x,va1.y,va1.z,va1.w};
        float fbv[8] = {vb0.x,vb0.y,vb0.z,vb0.w,vb1.x,vb1.y,vb1.z,vb1.w};
        #pragma unroll
        for (int j = 0; j < 8; ++j) {
            ah0[j] = (short)f2bf(fa[j]);
            ah1[j] = (short)f2bf(fbv[j]);
        }
        int kblk0 = kblk_base + step*2;
        #pragma unroll
        for (int fn = 0; fn < 4; ++fn) {
            size_t off0 = ((size_t)(kblk0*4 + fn)*64 + lane)*8;
            size_t off1 = ((size_t)((kblk0+1)*4 + fn)*64 + lane)*8;
            s8v bh0 = *reinterpret_cast<const s8v*>(fwT + off0);
            s8v bh1 = *reinterpret_cast<const s8v*>(fwT + off1);
            acc[fn] = __builtin_amdgcn_mfma_f32_16x16x32_bf16(ah0, bh0, acc[fn], 0, 0, 0);
            acc[fn] = __builtin_amdgcn_mfma_f32_16x16x32_bf16(ah1, bh1, acc[fn], 0, 0, 0);
        }
    }
    float* pout = part + (size_t)(mt*nks + ks)*4096;
    #pragma unroll
    for (int fn = 0; fn < 4; ++fn)
        #pragma unroll
        for (int r = 0; r < 4; ++r)
            pout[(w*16 + kg*4 + r)*64 + fn*16 + ml] = acc[fn][r];
}

// ---- D3: out — psum + softmax | sel load + A build + MFMA + stores ----
__global__ __launch_bounds__(256) void k_out(
        const float* __restrict__ part, const float* __restrict__ fb,
        const int* __restrict__ sel, const float* __restrict__ pool,
        const unsigned short* __restrict__ rwf, const float* __restrict__ rb,
        float* __restrict__ out, float* __restrict__ pad, int nks) {
    __shared__ float A_T[SIM][36];
    __shared__ float routeS[64];
    __shared__ int   selS[64];
    __shared__ float psum[4][64];
    int row = blockIdx.x;                    // b*64+p
    int b = row >> 6, p = row & 63;
    int t = threadIdx.x, lane = t & 63, w = t >> 6;
    int kpw = nks >> 2;
    {
        float v = 0.f;
        for (int kq = 0; kq < kpw; ++kq) {
            int ks = w*kpw + kq;
            v += part[(size_t)(b*nks + ks)*4096 + p*64 + lane];
        }
        psum[w][lane] = v;
    }
    __syncthreads();
    if (w == 0) {
        float v = psum[0][lane] + psum[1][lane] + psum[2][lane] + psum[3][lane] + fb[lane];
        float m = v;
        #pragma unroll
        for (int o = 32; o; o >>= 1) m = fmaxf(m, __shfl_xor(m, o));
        float e = expf(v - m);
        float sum = e;
        #pragma unroll
        for (int o = 32; o; o >>= 1) sum += __shfl_xor(sum, o);
        routeS[lane] = e / sum;
    } else if (w == 1) {
        selS[lane] = sel[p*SIM + lane];
    }
    __syncthreads();
    #pragma unroll
    for (int q = 0; q < 8; ++q) {            // A_T[s][l] = route[s]*pool[sel[s]][l]
        int e = t + q*256;
        int s = e >> 5, l = e & 31;
        A_T[s][l] = routeS[s] * pool[(size_t)selS[s]*PLEN + l];
    }
    __syncthreads();
    if (t < 32) {                            // padding row-sum
        float ps = 0.f;
        #pragma unroll
        for (int s = 0; s < 64; ++s) ps += A_T[s][t];
        pad[(size_t)b*2*SEQ + SEQ + p*PLEN + t] = ps;
    } else if (t < 64) {
        pad[(size_t)b*2*SEQ + p*PLEN + (t - 32)] = 0.f;
    }
    int ml = lane & 15, kg = lane >> 4;
    s8v ah[2][2];                            // [mt][ks], plain bf16
    #pragma unroll
    for (int mt = 0; mt < 2; ++mt)
        #pragma unroll
        for (int ks = 0; ks < 2; ++ks) {
            #pragma unroll
            for (int j = 0; j < 8; ++j)
                ah[mt][ks][j] = (short)f2bf(A_T[ks*32 + kg*8 + j][mt*16 + ml]);
        }
    size_t orow0 = ((size_t)(b*SEQ + p*PLEN))*DMODEL + HALFD;
    #pragma unroll
    for (int nt = 0; nt < 8; ++nt) {
        int fng = w*8 + nt;
        f32x4 acc0 = {}, acc1 = {};
        #pragma unroll
        for (int ks = 0; ks < 2; ++ks) {
            size_t off = ((size_t)(ks*32 + fng)*64 + lane)*8;
            s8v bh = *reinterpret_cast<const s8v*>(rwf + off);
            acc0 = __builtin_amdgcn_mfma_f32_16x16x32_bf16(ah[0][ks], bh, acc0, 0, 0, 0);
            acc1 = __builtin_amdgcn_mfma_f32_16x16x32_bf16(ah[1][ks], bh, acc1, 0, 0, 0);
        }
        int n = fng*16 + ml;
        float bias = rb[n];
        #pragma unroll
        for (int r = 0; r < 4; ++r) {
            int m0 = kg*4 + r;
            out[orow0 + (size_t)m0*DMODEL + n]        = acc0[r] + bias;
            out[orow0 + (size_t)(16 + m0)*DMODEL + n] = acc1[r] + bias;
        }
    }
}

static const void* by_size(void* const* d_in, const int* in_sizes, int n_in,
                           int want, int fallback) {
    for (int i = 0; i < n_in; ++i) if (in_sizes[i] == want) return d_in[i];
    return d_in[fallback];
}

extern "C" void kernel_launch(void* const* d_in, const int* in_sizes, int n_in,
                              void* d_out, int out_size, void* d_ws, size_t ws_size,
                              hipStream_t stream) {
    const float* src  = (const float*)by_size(d_in, in_sizes, n_in, NB*SEQ*DMODEL, 0);
    const float* pool = (const float*)by_size(d_in, in_sizes, n_in, PNUM*PLEN, 1);
    const float* fw   = (const float*)by_size(d_in, in_sizes, n_in, KDIM*SIM, 2);
    const float* fb   = (const float*)by_size(d_in, in_sizes, n_in, SIM, 3);
    const float* rw   = (const float*)by_size(d_in, in_sizes, n_in, SIM*HALFD, 4);
    const float* rb   = (const float*)by_size(d_in, in_sizes, n_in, HALFD, 5);
    const float* gpw  = (const float*)by_size(d_in, in_sizes, n_in, HALFD*10, 6);
    const float* gpb  = (const float*)by_size(d_in, in_sizes, n_in, 10, 7);
    float* out = (float*)d_out;
    float* pad = out + OUT0;

    int nks = (ws_size >= (size_t)(16u << 20)) ? 32 : 8;

    unsigned short* fwT = (unsigned short*)d_ws;                        // 2 MB
    unsigned short* rwf = fwT + (size_t)SIM*KDIM;                       // 64 KB
    u64*   cand  = (u64*)(rwf + (size_t)SIM*HALFD);                     // 256 KB
    int*   sel   = (int*)(cand + (size_t)NPATCH*8*SIM);                 // 16 KB
    float* part  = (float*)(sel + 4096);                                // nks * 256 KB

    hipLaunchKernelGGL(k_prep,   dim3(784),    dim3(256), 0, stream,
                       gpw, gpb, fw, rw, src, pool, fwT, rwf, cand);
    hipLaunchKernelGGL(k_logits, dim3(16*nks + NCOPY + NPATCH), dim3(256), 0, stream,
                       src, fwT, cand, part, out, sel, nks);
    hipLaunchKernelGGL(k_out,    dim3(MROWS),  dim3(256), 0, stream,
                       part, fb, sel, pool, rwf, rb, out, pad, nks);
}

// Round 19
// 88.951 us; speedup vs baseline: 1.2580x; 1.0190x over previous
//
#include <hip/hip_runtime.h>
#include <hip/hip_bf16.h>

#define NB 16
#define DMODEL 1024
#define HALFD 512
#define PNUM 4096
#define PLEN 32
#define SEQ 2048
#define SIM 64
#define NPATCH 64
#define NROWS (NB*SEQ)        // 32768 sequence rows
#define MROWS (NB*NPATCH)     // 1024 (b,p) rows
#define KDIM (PLEN*HALFD)     // 16384
#define NCOPY 512
#define OUT0 ((size_t)NB*SEQ*DMODEL)

typedef __attribute__((ext_vector_type(8))) short s8v;          // 8 bf16 (4 VGPR)
typedef __attribute__((ext_vector_type(4))) float f32x4;
typedef __attribute__((ext_vector_type(8))) unsigned short ush8;
typedef unsigned long long u64;

__device__ __forceinline__ unsigned short f2bf(float f) {
    __hip_bfloat16 h = __float2bfloat16(f);
    return *reinterpret_cast<unsigned short*>(&h);
}
__device__ __forceinline__ u64 umax64(u64 a, u64 b) { return a > b ? a : b; }
__device__ __forceinline__ u64 umin64(u64 a, u64 b) { return a < b ? a : b; }
__device__ __forceinline__ u64 clean6(u64 v, int lane) {
    #pragma unroll
    for (int j = 32; j; j >>= 1) {
        u64 o = __shfl_xor(v, j);
        v = ((lane & j) == 0) ? umax64(v, o) : umin64(v, o);
    }
    return v;
}

// ---- D1: topk self-contained (0..511) | fw pack (512..767) | rw pack (768..783) ----
union PrepShared {
    struct { double gpm[513]; double lowp[PLEN]; u64 wl[4][64]; } tk;  // 6.4 KB
    float tile[64][68];                                                // 17.4 KB
};
__global__ __launch_bounds__(256) void k_prep(
        const float* __restrict__ gp_w, const float* __restrict__ gp_b,
        const float* __restrict__ fw, const float* __restrict__ rw,
        const float* __restrict__ src, const float* __restrict__ pool,
        unsigned short* __restrict__ fwT, unsigned short* __restrict__ rwf,
        u64* __restrict__ cand) {
    __shared__ PrepShared u;
    int bid = blockIdx.x, t = threadIdx.x;
    int lane = t & 63, w = t >> 6;
    if (bid < 512) {
        int p = bid >> 3, q = bid & 7;
        for (int h = t; h < HALFD; h += 256) {
            double s = 0.0;
            #pragma unroll
            for (int j = 0; j < 10; ++j) s += (double)gp_w[h*10 + j];
            u.tk.gpm[h] = s / 10.0;
        }
        if (t == 0) {
            double sb = 0.0;
            #pragma unroll
            for (int j = 0; j < 10; ++j) sb += (double)gp_b[j];
            u.tk.gpm[512] = sb / 10.0;
        }
        __syncthreads();
        {   // lowp: wave w computes rows w*8..w*8+7 (batch-0 rows of patch p)
            const double* g0 = u.tk.gpm + lane*4;
            const double* g1 = u.tk.gpm + 256 + lane*4;
            #pragma unroll
            for (int rr = 0; rr < 8; ++rr) {
                int r = w*8 + rr;
                const float4* s4 = reinterpret_cast<const float4*>(src + (size_t)(p*PLEN + r)*DMODEL);
                float4 x0 = s4[128 + lane], x1 = s4[192 + lane];
                double d = (double)x0.x*g0[0] + (double)x0.y*g0[1] + (double)x0.z*g0[2] + (double)x0.w*g0[3]
                         + (double)x1.x*g1[0] + (double)x1.y*g1[1] + (double)x1.z*g1[2] + (double)x1.w*g1[3];
                #pragma unroll
                for (int o = 32; o; o >>= 1) d += __shfl_xor(d, o);
                if (lane == 0) u.tk.lowp[r] = d + u.tk.gpm[512];
            }
        }
        __syncthreads();
        u64 v[2];
        #pragma unroll
        for (int cc = 0; cc < 2; ++cc) {
            int n = q*512 + (w*2 + cc)*64 + lane;
            const float4* p4 = reinterpret_cast<const float4*>(pool + (size_t)n*PLEN);
            double s = 0.0;
            #pragma unroll
            for (int r2 = 0; r2 < 8; ++r2) {
                float4 vv = p4[r2];
                s += (double)vv.x*u.tk.lowp[r2*4] + (double)vv.y*u.tk.lowp[r2*4+1]
                   + (double)vv.z*u.tk.lowp[r2*4+2] + (double)vv.w*u.tk.lowp[r2*4+3];
            }
            u64 ub = (u64)__double_as_longlong(s);
            u64 okey = ub ^ (((u64)((long long)ub >> 63)) | 0x8000000000000000ULL);
            v[cc] = (okey & ~0xFFFULL) | (u64)(0xFFF - n);
        }
        #pragma unroll
        for (int kk = 2; kk <= 64; kk <<= 1) {
            #pragma unroll
            for (int j = kk >> 1; j; j >>= 1) {
                #pragma unroll
                for (int cc = 0; cc < 2; ++cc) {
                    u64 o = __shfl_xor(v[cc], j);
                    bool keepMax = ((lane & kk) == 0) == ((lane & j) == 0);
                    v[cc] = keepMax ? umax64(v[cc], o) : umin64(v[cc], o);
                }
            }
        }
        u64 rb2 = __shfl(v[1], 63 - lane);
        u64 m = umax64(v[0], rb2);
        m = clean6(m, lane);
        u.tk.wl[w][lane] = m;
        __syncthreads();
        if (w == 0) {
            u64 a = umax64(u.tk.wl[0][lane], u.tk.wl[1][63 - lane]); a = clean6(a, lane);
            u64 b = umax64(u.tk.wl[2][lane], u.tk.wl[3][63 - lane]); b = clean6(b, lane);
            u64 r2 = __shfl(b, 63 - lane);
            u64 f = umax64(a, r2); f = clean6(f, lane);
            cand[(size_t)(p*8 + q)*SIM + lane] = f;
        }
    } else if (bid < 768) {
        // ---- pack fw -> MFMA B-fragment order, plain bf16 ----
        int k0 = (bid - 512) * 64;
        int i = t >> 2;
        #pragma unroll
        for (int q = 0; q < 4; ++q) {
            int c = (t & 3) + q*4;
            float4 v = *reinterpret_cast<const float4*>(fw + (size_t)(k0 + i)*SIM + c*4);
            *reinterpret_cast<float4*>(&u.tile[i][c*4]) = v;
        }
        __syncthreads();
        #pragma unroll
        for (int c2 = 0; c2 < 2; ++c2) {
            int e = c2*256 + t;
            int kl = e >> 8, fn = (e >> 6) & 3, l = e & 63;
            int kk0 = kl*32 + ((l >> 4) * 8), n = fn*16 + (l & 15);
            ush8 hv;
            #pragma unroll
            for (int j = 0; j < 8; ++j) hv[j] = f2bf(u.tile[kk0 + j][n]);
            size_t dst = ((size_t)((2*(bid - 512) + kl)*4 + fn)*64 + l)*8;
            *reinterpret_cast<ush8*>(fwT + dst) = hv;
        }
    } else {
        // ---- pack rw (64x512) -> MFMA B-fragment order, plain bf16 ----
        int q = t >> 6;
        int idx = (bid - 768)*4 + q;           // 0..63 = (ks,fn)
        int ks = idx >> 5, fn = idx & 31;
        int ml = lane & 15, kg = lane >> 4;
        ush8 hv;
        #pragma unroll
        for (int j = 0; j < 8; ++j)
            hv[j] = f2bf(rw[(size_t)(ks*32 + kg*8 + j)*HALFD + fn*16 + ml]);
        size_t dst = ((size_t)idx*64 + lane)*8;
        *reinterpret_cast<ush8*>(rwf + dst) = hv;
    }
}

// ---- D2: logits MFMA (0..16*nks-1) | sel merge (next 64) ----
__global__ __launch_bounds__(256) void k_logits(
        const float* __restrict__ src, const unsigned short* __restrict__ fwT,
        const u64* __restrict__ cand, float* __restrict__ part,
        int* __restrict__ sel, int nks) {
    int t = threadIdx.x, lane = t & 63, w = t >> 6;
    int bid = blockIdx.x;
    int NL = 16*nks;
    if (bid >= NL) {
        // ---- sel merge role: one block per patch ----
        if (w != 0) return;
        int p = bid - NL;
        const u64* c = cand + (size_t)p*8*SIM;
        u64 a = umax64(c[lane],         c[1*SIM + 63 - lane]); a = clean6(a, lane);
        u64 bq = umax64(c[2*SIM + lane], c[3*SIM + 63 - lane]); bq = clean6(bq, lane);
        u64 d = umax64(c[4*SIM + lane], c[5*SIM + 63 - lane]); d = clean6(d, lane);
        u64 e = umax64(c[6*SIM + lane], c[7*SIM + 63 - lane]); e = clean6(e, lane);
        u64 ab = umax64(a, __shfl(bq, 63 - lane)); ab = clean6(ab, lane);
        u64 de = umax64(d, __shfl(e, 63 - lane)); de = clean6(de, lane);
        u64 f  = umax64(ab, __shfl(de, 63 - lane)); f = clean6(f, lane);
        sel[p*SIM + lane] = 0xFFF - (int)(f & 0xFFFULL);
        return;
    }
    int mt = bid / nks, ks = bid - mt*nks;
    int kchunk = KDIM / nks, nstep = kchunk >> 6;
    int r0 = mt*64;
    int ml = lane & 15, kg = lane >> 4;
    int Rrow = r0 + w*16 + ml;
    int bb = Rrow >> 6, prow = Rrow & 63;
    const float* xrow = src + ((size_t)(bb*SEQ + prow*PLEN))*DMODEL + HALFD;
    int kblk_base = (ks*kchunk) >> 5;
    f32x4 acc[4] = {};
    for (int step = 0; step < nstep; ++step) {
        int k0 = ks*kchunk + step*64;
        int l = k0 >> 9, h0 = k0 & 511;          // 64-chunk never crosses l
        const float* ap = xrow + (size_t)l*DMODEL + h0 + kg*8;
        float4 va0 = *reinterpret_cast<const float4*>(ap);
        float4 va1 = *reinterpret_cast<const float4*>(ap + 4);
        float4 vb0 = *reinterpret_cast<const float4*>(ap + 32);
        float4 vb1 = *reinterpret_cast<const float4*>(ap + 36);
        s8v ah0, ah1;
        float fa[8] = {va0.x,va0.y,va0.z,va0.w,va1.x,va1.y,va1.z,va1.w};
        float fbv[8] = {vb0.x,vb0.y,vb0.z,vb0.w,vb1.x,vb1.y,vb1.z,vb1.w};
        #pragma unroll
        for (int j = 0; j < 8; ++j) {
            ah0[j] = (short)f2bf(fa[j]);
            ah1[j] = (short)f2bf(fbv[j]);
        }
        int kblk0 = kblk_base + step*2;
        #pragma unroll
        for (int fn = 0; fn < 4; ++fn) {
            size_t off0 = ((size_t)(kblk0*4 + fn)*64 + lane)*8;
            size_t off1 = ((size_t)((kblk0+1)*4 + fn)*64 + lane)*8;
            s8v bh0 = *reinterpret_cast<const s8v*>(fwT + off0);
            s8v bh1 = *reinterpret_cast<const s8v*>(fwT + off1);
            acc[fn] = __builtin_amdgcn_mfma_f32_16x16x32_bf16(ah0, bh0, acc[fn], 0, 0, 0);
            acc[fn] = __builtin_amdgcn_mfma_f32_16x16x32_bf16(ah1, bh1, acc[fn], 0, 0, 0);
        }
    }
    float* pout = part + (size_t)(mt*nks + ks)*4096;
    #pragma unroll
    for (int fn = 0; fn < 4; ++fn)
        #pragma unroll
        for (int r = 0; r < 4; ++r)
            pout[(w*16 + kg*4 + r)*64 + fn*16 + ml] = acc[fn][r];
}

// ---- D3: copy (0..511) | out (512..1535): psum+softmax | sel + A build + MFMA + transposed stores ----
union OutShared {
    struct { float A_T[SIM][36]; float routeS[64]; int selS[64]; float psum[4][64]; } a;  // ~11 KB
    float xpose[16][516];                                                                 // 33 KB
};
__global__ __launch_bounds__(256) void k_out(
        const float* __restrict__ part, const float* __restrict__ fb,
        const int* __restrict__ sel, const float* __restrict__ pool,
        const unsigned short* __restrict__ rwf, const float* __restrict__ rb,
        const float* __restrict__ src, float* __restrict__ out,
        float* __restrict__ pad, int nks) {
    __shared__ OutShared u;
    int t = threadIdx.x, lane = t & 63, w = t >> 6;
    if (blockIdx.x < NCOPY) {
        // ---- copy role: out[:, :512] = src[:, :512] ----
        int cb = blockIdx.x;
        size_t total = (size_t)NROWS * 128;
        const float4* s4 = reinterpret_cast<const float4*>(src);
        float4* o4 = reinterpret_cast<float4*>(out);
        for (size_t idx = (size_t)cb*256 + t; idx < total; idx += (size_t)NCOPY*256) {
            size_t r = idx >> 7, c = idx & 127;
            o4[r*256 + c] = s4[r*256 + c];
        }
        return;
    }
    int row = blockIdx.x - NCOPY;            // b*64+p
    int b = row >> 6, p = row & 63;
    int kpw = nks >> 2;
    {
        float v = 0.f;
        for (int kq = 0; kq < kpw; ++kq) {
            int ks = w*kpw + kq;
            v += part[(size_t)(b*nks + ks)*4096 + p*64 + lane];
        }
        u.a.psum[w][lane] = v;
    }
    __syncthreads();
    if (w == 0) {
        float v = u.a.psum[0][lane] + u.a.psum[1][lane] + u.a.psum[2][lane] + u.a.psum[3][lane] + fb[lane];
        float m = v;
        #pragma unroll
        for (int o = 32; o; o >>= 1) m = fmaxf(m, __shfl_xor(m, o));
        float e = expf(v - m);
        float sum = e;
        #pragma unroll
        for (int o = 32; o; o >>= 1) sum += __shfl_xor(sum, o);
        u.a.routeS[lane] = e / sum;
    } else if (w == 1) {
        u.a.selS[lane] = sel[p*SIM + lane];
    }
    __syncthreads();
    #pragma unroll
    for (int q = 0; q < 8; ++q) {            // A_T[s][l] = route[s]*pool[sel[s]][l]
        int e = t + q*256;
        int s = e >> 5, l = e & 31;
        u.a.A_T[s][l] = u.a.routeS[s] * pool[(size_t)u.a.selS[s]*PLEN + l];
    }
    __syncthreads();
    if (t < 32) {                            // padding row-sum
        float ps = 0.f;
        #pragma unroll
        for (int s = 0; s < 64; ++s) ps += u.a.A_T[s][t];
        pad[(size_t)b*2*SEQ + SEQ + p*PLEN + t] = ps;
    } else if (t < 64) {
        pad[(size_t)b*2*SEQ + p*PLEN + (t - 32)] = 0.f;
    }
    int ml = lane & 15, kg = lane >> 4;
    s8v ah[2][2];                            // [mt][ks], plain bf16
    #pragma unroll
    for (int mt = 0; mt < 2; ++mt)
        #pragma unroll
        for (int ks = 0; ks < 2; ++ks) {
            #pragma unroll
            for (int j = 0; j < 8; ++j)
                ah[mt][ks][j] = (short)f2bf(u.a.A_T[ks*32 + kg*8 + j][mt*16 + ml]);
        }
    // MFMA: wave w covers N cols [w*128, w*128+128); bias folded in
    f32x4 accA[8], accB[8];
    #pragma unroll
    for (int nt = 0; nt < 8; ++nt) {
        int fng = w*8 + nt;
        f32x4 acc0 = {}, acc1 = {};
        #pragma unroll
        for (int ks = 0; ks < 2; ++ks) {
            size_t off = ((size_t)(ks*32 + fng)*64 + lane)*8;
            s8v bh = *reinterpret_cast<const s8v*>(rwf + off);
            acc0 = __builtin_amdgcn_mfma_f32_16x16x32_bf16(ah[0][ks], bh, acc0, 0, 0, 0);
            acc1 = __builtin_amdgcn_mfma_f32_16x16x32_bf16(ah[1][ks], bh, acc1, 0, 0, 0);
        }
        float bias = rb[fng*16 + ml];
        #pragma unroll
        for (int r = 0; r < 4; ++r) { acc0[r] += bias; acc1[r] += bias; }
        accA[nt] = acc0; accB[nt] = acc1;
    }
    // LDS-transpose stores: phase mt=0 rows 0..15, mt=1 rows 16..31
    size_t orow0 = ((size_t)(b*SEQ + p*PLEN))*DMODEL + HALFD;
    #pragma unroll
    for (int mt = 0; mt < 2; ++mt) {
        __syncthreads();
        #pragma unroll
        for (int nt = 0; nt < 8; ++nt) {
            f32x4 a = (mt == 0) ? accA[nt] : accB[nt];
            #pragma unroll
            for (int r = 0; r < 4; ++r)
                u.xpose[kg*4 + r][w*128 + nt*16 + ml] = a[r];
        }
        __syncthreads();
        #pragma unroll
        for (int q = 0; q < 8; ++q) {
            int e = q*256 + t;               // 16 rows x 128 float4
            int rr = e >> 7, c4 = e & 127;
            float4 v = *reinterpret_cast<float4*>(&u.xpose[rr][c4*4]);
            *reinterpret_cast<float4*>(out + orow0 + (size_t)(mt*16 + rr)*DMODEL + c4*4) = v;
        }
    }
}

static const void* by_size(void* const* d_in, const int* in_sizes, int n_in,
                           int want, int fallback) {
    for (int i = 0; i < n_in; ++i) if (in_sizes[i] == want) return d_in[i];
    return d_in[fallback];
}

extern "C" void kernel_launch(void* const* d_in, const int* in_sizes, int n_in,
                              void* d_out, int out_size, void* d_ws, size_t ws_size,
                              hipStream_t stream) {
    const float* src  = (const float*)by_size(d_in, in_sizes, n_in, NB*SEQ*DMODEL, 0);
    const float* pool = (const float*)by_size(d_in, in_sizes, n_in, PNUM*PLEN, 1);
    const float* fw   = (const float*)by_size(d_in, in_sizes, n_in, KDIM*SIM, 2);
    const float* fb   = (const float*)by_size(d_in, in_sizes, n_in, SIM, 3);
    const float* rw   = (const float*)by_size(d_in, in_sizes, n_in, SIM*HALFD, 4);
    const float* rb   = (const float*)by_size(d_in, in_sizes, n_in, HALFD, 5);
    const float* gpw  = (const float*)by_size(d_in, in_sizes, n_in, HALFD*10, 6);
    const float* gpb  = (const float*)by_size(d_in, in_sizes, n_in, 10, 7);
    float* out = (float*)d_out;
    float* pad = out + OUT0;

    int nks = (ws_size >= (size_t)(16u << 20)) ? 32 : 8;

    unsigned short* fwT = (unsigned short*)d_ws;                        // 2 MB
    unsigned short* rwf = fwT + (size_t)SIM*KDIM;                       // 64 KB
    u64*   cand  = (u64*)(rwf + (size_t)SIM*HALFD);                     // 256 KB
    int*   sel   = (int*)(cand + (size_t)NPATCH*8*SIM);                 // 16 KB
    float* part  = (float*)(sel + 4096);                                // nks * 256 KB

    hipLaunchKernelGGL(k_prep,   dim3(784),    dim3(256), 0, stream,
                       gpw, gpb, fw, rw, src, pool, fwT, rwf, cand);
    hipLaunchKernelGGL(k_logits, dim3(16*nks + NPATCH), dim3(256), 0, stream,
                       src, fwT, cand, part, sel, nks);
    hipLaunchKernelGGL(k_out,    dim3(NCOPY + MROWS), dim3(256), 0, stream,
                       part, fb, sel, pool, rwf, rb, src, out, pad, nks);
}

// Round 20
// 84.533 us; speedup vs baseline: 1.3237x; 1.0523x over previous
//
#include <hip/hip_runtime.h>
#include <hip/hip_bf16.h>

#define NB 16
#define DMODEL 1024
#define HALFD 512
#define PNUM 4096
#define PLEN 32
#define SEQ 2048
#define SIM 64
#define NPATCH 64
#define NROWS (NB*SEQ)        // 32768 sequence rows
#define MROWS (NB*NPATCH)     // 1024 (b,p) rows
#define KDIM (PLEN*HALFD)     // 16384
#define NCOPY 512
#define OUT0 ((size_t)NB*SEQ*DMODEL)

typedef __attribute__((ext_vector_type(8))) short s8v;          // 8 bf16 (4 VGPR)
typedef __attribute__((ext_vector_type(4))) float f32x4;
typedef __attribute__((ext_vector_type(8))) unsigned short ush8;
typedef unsigned long long u64;

__device__ __forceinline__ unsigned short f2bf(float f) {
    __hip_bfloat16 h = __float2bfloat16(f);
    return *reinterpret_cast<unsigned short*>(&h);
}
__device__ __forceinline__ u64 umax64(u64 a, u64 b) { return a > b ? a : b; }
__device__ __forceinline__ u64 umin64(u64 a, u64 b) { return a < b ? a : b; }
__device__ __forceinline__ u64 clean6(u64 v, int lane) {
    #pragma unroll
    for (int j = 32; j; j >>= 1) {
        u64 o = __shfl_xor(v, j);
        v = ((lane & j) == 0) ? umax64(v, o) : umin64(v, o);
    }
    return v;
}

// ---- D1: fw pack (0..255) | rw pack (256..271) — tiny, feeds D2 logits ----
__global__ __launch_bounds__(256) void k_pack(
        const float* __restrict__ fw, const float* __restrict__ rw,
        unsigned short* __restrict__ fwT, unsigned short* __restrict__ rwf) {
    __shared__ float tile[64][68];
    int bid = blockIdx.x, t = threadIdx.x;
    int lane = t & 63;
    if (bid < 256) {
        int k0 = bid * 64;
        int i = t >> 2;
        #pragma unroll
        for (int q = 0; q < 4; ++q) {
            int c = (t & 3) + q*4;
            float4 v = *reinterpret_cast<const float4*>(fw + (size_t)(k0 + i)*SIM + c*4);
            *reinterpret_cast<float4*>(&tile[i][c*4]) = v;
        }
        __syncthreads();
        #pragma unroll
        for (int c2 = 0; c2 < 2; ++c2) {
            int e = c2*256 + t;
            int kl = e >> 8, fn = (e >> 6) & 3, l = e & 63;
            int kk0 = kl*32 + ((l >> 4) * 8), n = fn*16 + (l & 15);
            ush8 hv;
            #pragma unroll
            for (int j = 0; j < 8; ++j) hv[j] = f2bf(tile[kk0 + j][n]);
            size_t dst = ((size_t)((2*bid + kl)*4 + fn)*64 + l)*8;
            *reinterpret_cast<ush8*>(fwT + dst) = hv;
        }
    } else {
        int q = t >> 6;
        int idx = (bid - 256)*4 + q;           // 0..63 = (ks,fn)
        int ks = idx >> 5, fn = idx & 31;
        int ml = lane & 15, kg = lane >> 4;
        ush8 hv;
        #pragma unroll
        for (int j = 0; j < 8; ++j)
            hv[j] = f2bf(rw[(size_t)(ks*32 + kg*8 + j)*HALFD + fn*16 + ml]);
        size_t dst = ((size_t)idx*64 + lane)*8;
        *reinterpret_cast<ush8*>(rwf + dst) = hv;
    }
}

// ---- D2: logits MFMA (0..16*nks-1) | topk self-contained (next 512) ----
__global__ __launch_bounds__(256) void k_mid(
        const float* __restrict__ src, const unsigned short* __restrict__ fwT,
        const float* __restrict__ pool,
        const float* __restrict__ gp_w, const float* __restrict__ gp_b,
        float* __restrict__ part, u64* __restrict__ cand, int nks) {
    int t = threadIdx.x, lane = t & 63, w = t >> 6;
    int bid = blockIdx.x;
    int NL = 16*nks;
    if (bid >= NL) {
        // ---- topk role: own gp means + own lowp + scores + wave-reg bitonic ----
        __shared__ struct { double gpm[513]; double lowp[PLEN]; u64 wl[4][64]; } u;
        int tb = bid - NL;
        int p = tb >> 3, q = tb & 7;
        for (int h = t; h < HALFD; h += 256) {
            double s = 0.0;
            #pragma unroll
            for (int j = 0; j < 10; ++j) s += (double)gp_w[h*10 + j];
            u.gpm[h] = s / 10.0;
        }
        if (t == 0) {
            double sb = 0.0;
            #pragma unroll
            for (int j = 0; j < 10; ++j) sb += (double)gp_b[j];
            u.gpm[512] = sb / 10.0;
        }
        __syncthreads();
        {   // lowp: wave w computes rows w*8..w*8+7 (batch-0 rows of patch p)
            const double* g0 = u.gpm + lane*4;
            const double* g1 = u.gpm + 256 + lane*4;
            #pragma unroll
            for (int rr = 0; rr < 8; ++rr) {
                int r = w*8 + rr;
                const float4* s4 = reinterpret_cast<const float4*>(src + (size_t)(p*PLEN + r)*DMODEL);
                float4 x0 = s4[128 + lane], x1 = s4[192 + lane];
                double d = (double)x0.x*g0[0] + (double)x0.y*g0[1] + (double)x0.z*g0[2] + (double)x0.w*g0[3]
                         + (double)x1.x*g1[0] + (double)x1.y*g1[1] + (double)x1.z*g1[2] + (double)x1.w*g1[3];
                #pragma unroll
                for (int o = 32; o; o >>= 1) d += __shfl_xor(d, o);
                if (lane == 0) u.lowp[r] = d + u.gpm[512];
            }
        }
        __syncthreads();
        u64 v[2];
        #pragma unroll
        for (int cc = 0; cc < 2; ++cc) {
            int n = q*512 + (w*2 + cc)*64 + lane;
            const float4* p4 = reinterpret_cast<const float4*>(pool + (size_t)n*PLEN);
            double s = 0.0;
            #pragma unroll
            for (int r2 = 0; r2 < 8; ++r2) {
                float4 vv = p4[r2];
                s += (double)vv.x*u.lowp[r2*4] + (double)vv.y*u.lowp[r2*4+1]
                   + (double)vv.z*u.lowp[r2*4+2] + (double)vv.w*u.lowp[r2*4+3];
            }
            u64 ub = (u64)__double_as_longlong(s);
            u64 okey = ub ^ (((u64)((long long)ub >> 63)) | 0x8000000000000000ULL);
            v[cc] = (okey & ~0xFFFULL) | (u64)(0xFFF - n);
        }
        #pragma unroll
        for (int kk = 2; kk <= 64; kk <<= 1) {
            #pragma unroll
            for (int j = kk >> 1; j; j >>= 1) {
                #pragma unroll
                for (int cc = 0; cc < 2; ++cc) {
                    u64 o = __shfl_xor(v[cc], j);
                    bool keepMax = ((lane & kk) == 0) == ((lane & j) == 0);
                    v[cc] = keepMax ? umax64(v[cc], o) : umin64(v[cc], o);
                }
            }
        }
        u64 rb2 = __shfl(v[1], 63 - lane);
        u64 m = umax64(v[0], rb2);
        m = clean6(m, lane);
        u.wl[w][lane] = m;
        __syncthreads();
        if (w == 0) {
            u64 a = umax64(u.wl[0][lane], u.wl[1][63 - lane]); a = clean6(a, lane);
            u64 b = umax64(u.wl[2][lane], u.wl[3][63 - lane]); b = clean6(b, lane);
            u64 r2 = __shfl(b, 63 - lane);
            u64 f = umax64(a, r2); f = clean6(f, lane);
            cand[(size_t)(p*8 + q)*SIM + lane] = f;
        }
        return;
    }
    int mt = bid / nks, ks = bid - mt*nks;
    int kchunk = KDIM / nks, nstep = kchunk >> 6;
    int r0 = mt*64;
    int ml = lane & 15, kg = lane >> 4;
    int Rrow = r0 + w*16 + ml;
    int bb = Rrow >> 6, prow = Rrow & 63;
    const float* xrow = src + ((size_t)(bb*SEQ + prow*PLEN))*DMODEL + HALFD;
    int kblk_base = (ks*kchunk) >> 5;
    f32x4 acc[4] = {};
    for (int step = 0; step < nstep; ++step) {
        int k0 = ks*kchunk + step*64;
        int l = k0 >> 9, h0 = k0 & 511;          // 64-chunk never crosses l
        const float* ap = xrow + (size_t)l*DMODEL + h0 + kg*8;
        float4 va0 = *reinterpret_cast<const float4*>(ap);
        float4 va1 = *reinterpret_cast<const float4*>(ap + 4);
        float4 vb0 = *reinterpret_cast<const float4*>(ap + 32);
        float4 vb1 = *reinterpret_cast<const float4*>(ap + 36);
        s8v ah0, ah1;
        float fa[8] = {va0.x,va0.y,va0.z,va0.w,va1.x,va1.y,va1.z,va1.w};
        float fbv[8] = {vb0.x,vb0.y,vb0.z,vb0.w,vb1.x,vb1.y,vb1.z,vb1.w};
        #pragma unroll
        for (int j = 0; j < 8; ++j) {
            ah0[j] = (short)f2bf(fa[j]);
            ah1[j] = (short)f2bf(fbv[j]);
        }
        int kblk0 = kblk_base + step*2;
        #pragma unroll
        for (int fn = 0; fn < 4; ++fn) {
            size_t off0 = ((size_t)(kblk0*4 + fn)*64 + lane)*8;
            size_t off1 = ((size_t)((kblk0+1)*4 + fn)*64 + lane)*8;
            s8v bh0 = *reinterpret_cast<const s8v*>(fwT + off0);
            s8v bh1 = *reinterpret_cast<const s8v*>(fwT + off1);
            acc[fn] = __builtin_amdgcn_mfma_f32_16x16x32_bf16(ah0, bh0, acc[fn], 0, 0, 0);
            acc[fn] = __builtin_amdgcn_mfma_f32_16x16x32_bf16(ah1, bh1, acc[fn], 0, 0, 0);
        }
    }
    float* pout = part + (size_t)(mt*nks + ks)*4096;
    #pragma unroll
    for (int fn = 0; fn < 4; ++fn)
        #pragma unroll
        for (int r = 0; r < 4; ++r)
            pout[(w*16 + kg*4 + r)*64 + fn*16 + ml] = acc[fn][r];
}

// ---- D3: copy (0..511) | out (512..1535): psum + softmax | in-block merge + A build + MFMA + transposed stores ----
union OutShared {
    struct { float A_T[SIM][36]; float routeS[64]; int selS[64]; float psum[4][64]; } a;  // ~11 KB
    float xpose[16][516];                                                                 // 33 KB
};
__global__ __launch_bounds__(256) void k_out(
        const float* __restrict__ part, const float* __restrict__ fb,
        const u64* __restrict__ cand, const float* __restrict__ pool,
        const unsigned short* __restrict__ rwf, const float* __restrict__ rb,
        const float* __restrict__ src, float* __restrict__ out,
        float* __restrict__ pad, int nks) {
    __shared__ OutShared u;
    int t = threadIdx.x, lane = t & 63, w = t >> 6;
    if (blockIdx.x < NCOPY) {
        // ---- copy role: out[:, :512] = src[:, :512] ----
        int cb = blockIdx.x;
        size_t total = (size_t)NROWS * 128;
        const float4* s4 = reinterpret_cast<const float4*>(src);
        float4* o4 = reinterpret_cast<float4*>(out);
        for (size_t idx = (size_t)cb*256 + t; idx < total; idx += (size_t)NCOPY*256) {
            size_t r = idx >> 7, c = idx & 127;
            o4[r*256 + c] = s4[r*256 + c];
        }
        return;
    }
    int row = blockIdx.x - NCOPY;            // b*64+p
    int b = row >> 6, p = row & 63;
    int kpw = nks >> 2;
    {
        float v = 0.f;
        for (int kq = 0; kq < kpw; ++kq) {
            int ks = w*kpw + kq;
            v += part[(size_t)(b*nks + ks)*4096 + p*64 + lane];
        }
        u.a.psum[w][lane] = v;
    }
    __syncthreads();
    if (w == 0) {
        float v = u.a.psum[0][lane] + u.a.psum[1][lane] + u.a.psum[2][lane] + u.a.psum[3][lane] + fb[lane];
        float m = v;
        #pragma unroll
        for (int o = 32; o; o >>= 1) m = fmaxf(m, __shfl_xor(m, o));
        float e = expf(v - m);
        float sum = e;
        #pragma unroll
        for (int o = 32; o; o >>= 1) sum += __shfl_xor(sum, o);
        u.a.routeS[lane] = e / sum;
    } else if (w == 1) {
        const u64* c = cand + (size_t)p*8*SIM;
        u64 a = umax64(c[lane],         c[1*SIM + 63 - lane]); a = clean6(a, lane);
        u64 bq = umax64(c[2*SIM + lane], c[3*SIM + 63 - lane]); bq = clean6(bq, lane);
        u64 d = umax64(c[4*SIM + lane], c[5*SIM + 63 - lane]); d = clean6(d, lane);
        u64 e = umax64(c[6*SIM + lane], c[7*SIM + 63 - lane]); e = clean6(e, lane);
        u64 ab = umax64(a, __shfl(bq, 63 - lane)); ab = clean6(ab, lane);
        u64 de = umax64(d, __shfl(e, 63 - lane)); de = clean6(de, lane);
        u64 f  = umax64(ab, __shfl(de, 63 - lane)); f = clean6(f, lane);
        u.a.selS[lane] = 0xFFF - (int)(f & 0xFFFULL);
    }
    __syncthreads();
    #pragma unroll
    for (int q = 0; q < 8; ++q) {            // A_T[s][l] = route[s]*pool[sel[s]][l]
        int e = t + q*256;
        int s = e >> 5, l = e & 31;
        u.a.A_T[s][l] = u.a.routeS[s] * pool[(size_t)u.a.selS[s]*PLEN + l];
    }
    __syncthreads();
    if (t < 32) {                            // padding row-sum
        float ps = 0.f;
        #pragma unroll
        for (int s = 0; s < 64; ++s) ps += u.a.A_T[s][t];
        pad[(size_t)b*2*SEQ + SEQ + p*PLEN + t] = ps;
    } else if (t < 64) {
        pad[(size_t)b*2*SEQ + p*PLEN + (t - 32)] = 0.f;
    }
    int ml = lane & 15, kg = lane >> 4;
    s8v ah[2][2];                            // [mt][ks], plain bf16
    #pragma unroll
    for (int mt = 0; mt < 2; ++mt)
        #pragma unroll
        for (int ks = 0; ks < 2; ++ks) {
            #pragma unroll
            for (int j = 0; j < 8; ++j)
                ah[mt][ks][j] = (short)f2bf(u.a.A_T[ks*32 + kg*8 + j][mt*16 + ml]);
        }
    // MFMA: wave w covers N cols [w*128, w*128+128); bias folded in
    f32x4 accA[8], accB[8];
    #pragma unroll
    for (int nt = 0; nt < 8; ++nt) {
        int fng = w*8 + nt;
        f32x4 acc0 = {}, acc1 = {};
        #pragma unroll
        for (int ks = 0; ks < 2; ++ks) {
            size_t off = ((size_t)(ks*32 + fng)*64 + lane)*8;
            s8v bh = *reinterpret_cast<const s8v*>(rwf + off);
            acc0 = __builtin_amdgcn_mfma_f32_16x16x32_bf16(ah[0][ks], bh, acc0, 0, 0, 0);
            acc1 = __builtin_amdgcn_mfma_f32_16x16x32_bf16(ah[1][ks], bh, acc1, 0, 0, 0);
        }
        float bias = rb[fng*16 + ml];
        #pragma unroll
        for (int r = 0; r < 4; ++r) { acc0[r] += bias; acc1[r] += bias; }
        accA[nt] = acc0; accB[nt] = acc1;
    }
    // LDS-transpose stores: phase mt=0 rows 0..15, mt=1 rows 16..31
    size_t orow0 = ((size_t)(b*SEQ + p*PLEN))*DMODEL + HALFD;
    #pragma unroll
    for (int mt = 0; mt < 2; ++mt) {
        __syncthreads();
        #pragma unroll
        for (int nt = 0; nt < 8; ++nt) {
            f32x4 a = (mt == 0) ? accA[nt] : accB[nt];
            #pragma unroll
            for (int r = 0; r < 4; ++r)
                u.xpose[kg*4 + r][w*128 + nt*16 + ml] = a[r];
        }
        __syncthreads();
        #pragma unroll
        for (int q = 0; q < 8; ++q) {
            int e = q*256 + t;               // 16 rows x 128 float4
            int rr = e >> 7, c4 = e & 127;
            float4 v = *reinterpret_cast<float4*>(&u.xpose[rr][c4*4]);
            *reinterpret_cast<float4*>(out + orow0 + (size_t)(mt*16 + rr)*DMODEL + c4*4) = v;
        }
    }
}

static const void* by_size(void* const* d_in, const int* in_sizes, int n_in,
                           int want, int fallback) {
    for (int i = 0; i < n_in; ++i) if (in_sizes[i] == want) return d_in[i];
    return d_in[fallback];
}

extern "C" void kernel_launch(void* const* d_in, const int* in_sizes, int n_in,
                              void* d_out, int out_size, void* d_ws, size_t ws_size,
                              hipStream_t stream) {
    const float* src  = (const float*)by_size(d_in, in_sizes, n_in, NB*SEQ*DMODEL, 0);
    const float* pool = (const float*)by_size(d_in, in_sizes, n_in, PNUM*PLEN, 1);
    const float* fw   = (const float*)by_size(d_in, in_sizes, n_in, KDIM*SIM, 2);
    const float* fb   = (const float*)by_size(d_in, in_sizes, n_in, SIM, 3);
    const float* rw   = (const float*)by_size(d_in, in_sizes, n_in, SIM*HALFD, 4);
    const float* rb   = (const float*)by_size(d_in, in_sizes, n_in, HALFD, 5);
    const float* gpw  = (const float*)by_size(d_in, in_sizes, n_in, HALFD*10, 6);
    const float* gpb  = (const float*)by_size(d_in, in_sizes, n_in, 10, 7);
    float* out = (float*)d_out;
    float* pad = out + OUT0;

    int nks = (ws_size >= (size_t)(16u << 20)) ? 32 : 8;

    unsigned short* fwT = (unsigned short*)d_ws;                        // 2 MB
    unsigned short* rwf = fwT + (size_t)SIM*KDIM;                       // 64 KB
    u64*   cand  = (u64*)(rwf + (size_t)SIM*HALFD);                     // 256 KB
    float* part  = (float*)(cand + (size_t)NPATCH*8*SIM);               // nks * 256 KB

    hipLaunchKernelGGL(k_pack, dim3(272),          dim3(256), 0, stream, fw, rw, fwT, rwf);
    hipLaunchKernelGGL(k_mid,  dim3(16*nks + 512), dim3(256), 0, stream,
                       src, fwT, pool, gpw, gpb, part, cand, nks);
    hipLaunchKernelGGL(k_out,  dim3(NCOPY + MROWS), dim3(256), 0, stream,
                       part, fb, cand, pool, rwf, rb, src, out, pad, nks);
}